// Round 6
// baseline (282.667 us; speedup 1.0000x reference)
//
#include <hip/hip_runtime.h>

// Problem constants
#define NITEMS 50000
#define EMBD   16
#define NSLATE 10
#define HIDD   512
#define LATD   64
#define RESPD  1024
#define BATCH  256
#define NPCH   10     // pool chunks: 50000/10 = 5000 items = 1250 int4 per chunk
#define PI4    1250   // int4s per pool chunk
#define BG     4      // batches per pool block (emb row loaded once, used 4x)
#define LOG2E  1.44269504088896340736f
#define SHIFT  64.0f  // fixed log2-domain shift: s = sum exp2(x*log2e - 64)

// MFMA scoring config: logits = rx[2560x16] @ emb^T[16x50000] via v_mfma_f32_32x32x16_bf16
// Each wave owns FOUR 32-col groups (C=4) -> split/loads amortized over 24 MFMAs.
#define NCOL   2560   // BATCH*NSLATE output columns
#define NT     1563   // ceil(50000/32) item tiles (last tile has 16 pad rows)
#define IC     128    // item chunks (grid.y)
#define TPC    13     // tiles per chunk: 128*13 = 1664 >= 1563

// d_out layout (float): z_mean[256*64] | z_log_var[256*64] | recon_slate[256*10] | recon_resp[256*10]
#define OUT_ZM 0
#define OUT_ZLV 16384
#define OUT_RS 32768
#define OUT_RR 35328

// ws layout (floats), with time-overlays (all dispatches stream-ordered):
//   [0 .. 589824)        x[307200] + dz[282624]  (build_x -> enc / d1)
//                        OVERLAY p2[8*40960=327680] (gemm_d2 -> rx_prep)
//   [0 .. 983040)        OVERLAY score partials ps/pm/pa [3*128*2560=983040]
//                        (score_mfma -> score_final; x/dz/p2/pp/part all dead by then)
//   [589824 .. 868352)   pool partials pp [64bg*10c*4wv*68 = 174080 used] (pool_part -> build_x)
//   [589824 .. 1114112)  OVERLAY part[4*131072] (enc->mulv_z, d1->gemm_d2)
//   [1114112 .. 1155072) rx[40960] f32, LOG2E-scaled (rx_prep -> score_final)
//   [1155072 .. 1216512) rx bf16 3-way split rx0/rx1/rx2 [3*40960 ushort = 3*20480 float-slots]
// total 1216512 floats = 4.87 MB (identical to known-safe footprint)
#define WS_X    0
#define WS_DZ   307200
#define WS_P2   0
#define WS_PS   0
#define WS_PM   327680
#define WS_PA   655360
#define WS_PP   589824
#define WS_PART 589824
#define WS_RX   1114112
#define WS_RXS0 1155072
#define WS_RXS1 1175552
#define WS_RXS2 1196032

typedef __attribute__((ext_vector_type(8))) short bfrag;    // 8 bf16 = 4 VGPR (A/B operand)
typedef __attribute__((ext_vector_type(16))) float f32x16;  // C/D operand

// round-to-nearest-even f32 -> bf16, returned as f32 with low mantissa zeroed
__device__ __forceinline__ float bfround(float v) {
  unsigned u = __float_as_uint(v);
  unsigned r = (u + 0x7FFFu + ((u >> 16) & 1u)) & 0xFFFF0000u;
  return __uint_as_float(r);
}

// Pool partials: grid (64 bg, 10 c), BG=4 batches per block. BRANCH-FREE weighted
// accumulate: acc = fmaf((float)u, e, acc) -- bitwise identical to conditional add
// (w=1 exact add, w=0 adds +0) but with NO control dependence, so all emb loads
// issue unconditionally and pipeline deep. emb row loaded once per block, applied
// to 4 batches -> L2 gather traffic /4. Per-wave partial: [4 batches][17] -> pp.
__global__ __launch_bounds__(256) void pool_part(const int* __restrict__ u,
    const float* __restrict__ emb, float* __restrict__ pp) {
  int bg = blockIdx.x, c = blockIdx.y, t = threadIdx.x;
  float acc[BG][17];
  #pragma unroll
  for (int j = 0; j < BG; ++j)
    #pragma unroll
    for (int i = 0; i < 17; ++i) acc[j][i] = 0.0f;
  const int4* ub = (const int4*)u;
  size_t base = (size_t)(bg * BG) * 12500 + (size_t)c * PI4;
  int nBase = c * 5000;
  for (int i4 = t; i4 < PI4; i4 += 256) {
    int4 u0 = ub[base + i4];
    int4 u1 = ub[base + 12500 + i4];
    int4 u2 = ub[base + 25000 + i4];
    int4 u3 = ub[base + 37500 + i4];
    int w[BG][4] = {{u0.x, u0.y, u0.z, u0.w}, {u1.x, u1.y, u1.z, u1.w},
                    {u2.x, u2.y, u2.z, u2.w}, {u3.x, u3.y, u3.z, u3.w}};
    const float4* e4 = (const float4*)(emb + (size_t)(nBase + i4 * 4) * 16);
    #pragma unroll
    for (int it = 0; it < 4; ++it) {
      float4 ea = e4[it * 4 + 0], eb = e4[it * 4 + 1];
      float4 ec = e4[it * 4 + 2], ed = e4[it * 4 + 3];
      #pragma unroll
      for (int j = 0; j < BG; ++j) {
        float wf = (float)w[j][it];
        acc[j][0]  = fmaf(wf, ea.x, acc[j][0]);
        acc[j][1]  = fmaf(wf, ea.y, acc[j][1]);
        acc[j][2]  = fmaf(wf, ea.z, acc[j][2]);
        acc[j][3]  = fmaf(wf, ea.w, acc[j][3]);
        acc[j][4]  = fmaf(wf, eb.x, acc[j][4]);
        acc[j][5]  = fmaf(wf, eb.y, acc[j][5]);
        acc[j][6]  = fmaf(wf, eb.z, acc[j][6]);
        acc[j][7]  = fmaf(wf, eb.w, acc[j][7]);
        acc[j][8]  = fmaf(wf, ec.x, acc[j][8]);
        acc[j][9]  = fmaf(wf, ec.y, acc[j][9]);
        acc[j][10] = fmaf(wf, ec.z, acc[j][10]);
        acc[j][11] = fmaf(wf, ec.w, acc[j][11]);
        acc[j][12] = fmaf(wf, ed.x, acc[j][12]);
        acc[j][13] = fmaf(wf, ed.y, acc[j][13]);
        acc[j][14] = fmaf(wf, ed.z, acc[j][14]);
        acc[j][15] = fmaf(wf, ed.w, acc[j][15]);
        acc[j][16] += wf;
      }
    }
  }
  #pragma unroll
  for (int off = 32; off > 0; off >>= 1) {
    #pragma unroll
    for (int j = 0; j < BG; ++j)
      #pragma unroll
      for (int i = 0; i < 17; ++i) acc[j][i] += __shfl_down(acc[j][i], off);
  }
  int lane = t & 63, wv = t >> 6;
  if (lane == 0) {
    float* dst = pp + (size_t)((bg * NPCH + c) * 4 + wv) * (BG * 17);
    #pragma unroll
    for (int j = 0; j < BG; ++j)
      #pragma unroll
      for (int i = 0; i < 17; ++i) dst[j * 17 + i] = acc[j][i];
  }
}

// Sum 40 wave-partials per b; build x = [slate(160)|user(16)|resp(1024)],
// dz[64:1104] = [user|resp].
__global__ __launch_bounds__(256) void build_x(const float* __restrict__ pp,
    const int* __restrict__ slate, const float* __restrict__ resp,
    const float* __restrict__ emb, float* __restrict__ x, float* __restrict__ dz) {
  __shared__ float fin[17];
  int b = blockIdx.x, t = threadIdx.x;
  if (t < 17) {
    int bg = b >> 2, j = b & 3;
    float a = 0.f;
    const float* p = pp + (size_t)(bg * NPCH * 4) * (BG * 17) + j * 17 + t;
    #pragma unroll
    for (int w = 0; w < NPCH * 4; ++w) a += p[(size_t)w * (BG * 17)];
    fin[t] = a;
  }
  __syncthreads();
  float inv = 1.0f / fin[16];
  if (t < 16) {
    float uv = fin[t] * inv;
    x[b * 1200 + 160 + t] = uv;
    dz[b * 1104 + 64 + t] = uv;
  }
  if (t >= 32 && t < 192) {
    int i = t - 32;
    int k = i >> 4, e = i & 15;
    int it = slate[b * 10 + k];
    x[b * 1200 + i] = emb[(size_t)it * 16 + e];
  }
  for (int i = t; i < 1024; i += 256) {
    float r = resp[b * 1024 + i];
    x[b * 1200 + 176 + i] = r;
    dz[b * 1104 + 80 + i] = r;
  }
}

// Split-K partial GEMM: P[z][M,N] = A[M,ks:ke] @ B[N,ks:ke]^T
__global__ __launch_bounds__(256) void gemm64(const float* __restrict__ A,
    const float* __restrict__ B, float* __restrict__ P, int M, int N, int K, int kChunk) {
  __shared__ float As[16][68];  // As[kk][m]
  __shared__ float Bs[16][68];  // Bs[kk][n]
  int tid = threadIdx.x;
  int m0 = blockIdx.y * 64, n0 = blockIdx.x * 64;
  int ks = blockIdx.z * kChunk;
  int ke = ks + kChunk; if (ke > K) ke = K;
  int sr = tid >> 2;          // 0..63
  int sc = (tid & 3) * 4;     // 0,4,8,12
  int tx = tid & 15, ty = tid >> 4;
  float acc[4][4];
  #pragma unroll
  for (int i = 0; i < 4; ++i)
    #pragma unroll
    for (int j = 0; j < 4; ++j) acc[i][j] = 0.f;
  for (int k0 = ks; k0 < ke; k0 += 16) {
    float4 av = make_float4(0.f, 0.f, 0.f, 0.f);
    float4 bv = make_float4(0.f, 0.f, 0.f, 0.f);
    if (k0 + sc < ke)
      av = *(const float4*)(A + (size_t)(m0 + sr) * K + k0 + sc);
    if (k0 + sc < ke && n0 + sr < N)
      bv = *(const float4*)(B + (size_t)(n0 + sr) * K + k0 + sc);
    __syncthreads();
    As[sc][sr] = av.x; As[sc + 1][sr] = av.y; As[sc + 2][sr] = av.z; As[sc + 3][sr] = av.w;
    Bs[sc][sr] = bv.x; Bs[sc + 1][sr] = bv.y; Bs[sc + 2][sr] = bv.z; Bs[sc + 3][sr] = bv.w;
    __syncthreads();
    #pragma unroll
    for (int kk = 0; kk < 16; ++kk) {
      float4 a4 = *(const float4*)&As[kk][4 * ty];
      float4 b4 = *(const float4*)&Bs[kk][4 * tx];
      float a[4] = {a4.x, a4.y, a4.z, a4.w};
      float b[4] = {b4.x, b4.y, b4.z, b4.w};
      #pragma unroll
      for (int i = 0; i < 4; ++i)
        #pragma unroll
        for (int j = 0; j < 4; ++j) acc[i][j] = fmaf(a[i], b[j], acc[i][j]);
    }
  }
  float* Pz = P + (size_t)blockIdx.z * M * N;
  #pragma unroll
  for (int i = 0; i < 4; ++i) {
    int m = m0 + 4 * ty + i, n = n0 + 4 * tx;
    if (n < N)
      *(float4*)(Pz + (size_t)m * N + n) = make_float4(acc[i][0], acc[i][1], acc[i][2], acc[i][3]);
  }
}

// h = relu(sum_s part[s] + b_enc); z_mean/z_log_var -> out; z -> dz[0:64]
__global__ __launch_bounds__(128) void mulv_z_kernel(const float* __restrict__ part,
    const float* __restrict__ benc,
    const float* __restrict__ Wmu, const float* __restrict__ bmu,
    const float* __restrict__ Wlv, const float* __restrict__ blv,
    const float* __restrict__ eps, float* __restrict__ out, float* __restrict__ dz) {
  __shared__ __align__(16) float hs[512];
  __shared__ float zms[64], zlvs[64];
  int b = blockIdx.x, t = threadIdx.x;
  for (int i = t; i < 512; i += 128) {
    float a = benc[i];
    #pragma unroll
    for (int s = 0; s < 4; ++s) a += part[(size_t)s * 131072 + b * 512 + i];
    hs[i] = fmaxf(a, 0.f);
  }
  __syncthreads();
  const float* Wr = (t < 64) ? (Wmu + (size_t)t * 512) : (Wlv + (size_t)(t - 64) * 512);
  float bias = (t < 64) ? bmu[t] : blv[t - 64];
  const float4* w4 = (const float4*)Wr;
  const float4* h4 = (const float4*)hs;
  float a0 = 0.f, a1 = 0.f, a2 = 0.f, a3 = 0.f;
  #pragma unroll 4
  for (int i = 0; i < 128; ++i) {
    float4 w = w4[i], hv = h4[i];
    a0 = fmaf(w.x, hv.x, a0); a1 = fmaf(w.y, hv.y, a1);
    a2 = fmaf(w.z, hv.z, a2); a3 = fmaf(w.w, hv.w, a3);
  }
  float acc = (a0 + a1) + (a2 + a3) + bias;
  if (t < 64) { out[OUT_ZM + b * 64 + t] = acc; zms[t] = acc; }
  else        { out[OUT_ZLV + b * 64 + (t - 64)] = acc; zlvs[t - 64] = acc; }
  __syncthreads();
  if (t < 64) {
    float zv = fmaf(eps[b * 64 + t], __builtin_amdgcn_exp2f(0.7213475204444817f * zlvs[t]), zms[t]);
    dz[b * 1104 + t] = zv;
  }
}

// d2 split-K GEMM with reduce-on-load: A[m][k] = relu(sum_s part[s][m*512+k] + b_d1[k]),
// P2[z] = A[:, z*64:(z+1)*64] @ W_d2[:, same]^T. Grid (3,4,8). Bias/relu/scale in rx_prep.
__global__ __launch_bounds__(256) void gemm_d2(const float* __restrict__ part,
    const float* __restrict__ bd1, const float* __restrict__ W, float* __restrict__ p2) {
  __shared__ float As[16][68];
  __shared__ float Bs[16][68];
  const int N = 160;
  int tid = threadIdx.x;
  int m0 = blockIdx.y * 64, n0 = blockIdx.x * 64;
  int ks = blockIdx.z * 64, ke = ks + 64;
  int sr = tid >> 2, sc = (tid & 3) * 4;
  int tx = tid & 15, ty = tid >> 4;
  float acc[4][4];
  #pragma unroll
  for (int i = 0; i < 4; ++i)
    #pragma unroll
    for (int j = 0; j < 4; ++j) acc[i][j] = 0.f;
  for (int k0 = ks; k0 < ke; k0 += 16) {
    int col = k0 + sc;
    const float* p = part + (size_t)(m0 + sr) * 512 + col;
    float4 a0 = *(const float4*)(p);
    float4 a1 = *(const float4*)(p + 131072);
    float4 a2 = *(const float4*)(p + 262144);
    float4 a3 = *(const float4*)(p + 393216);
    float4 bb = *(const float4*)(bd1 + col);
    float4 av;
    av.x = fmaxf(a0.x + a1.x + a2.x + a3.x + bb.x, 0.f);
    av.y = fmaxf(a0.y + a1.y + a2.y + a3.y + bb.y, 0.f);
    av.z = fmaxf(a0.z + a1.z + a2.z + a3.z + bb.z, 0.f);
    av.w = fmaxf(a0.w + a1.w + a2.w + a3.w + bb.w, 0.f);
    float4 bv = make_float4(0.f, 0.f, 0.f, 0.f);
    if (n0 + sr < N)
      bv = *(const float4*)(W + (size_t)(n0 + sr) * 512 + col);
    __syncthreads();
    As[sc][sr] = av.x; As[sc + 1][sr] = av.y; As[sc + 2][sr] = av.z; As[sc + 3][sr] = av.w;
    Bs[sc][sr] = bv.x; Bs[sc + 1][sr] = bv.y; Bs[sc + 2][sr] = bv.z; Bs[sc + 3][sr] = bv.w;
    __syncthreads();
    #pragma unroll
    for (int kk = 0; kk < 16; ++kk) {
      float4 a4 = *(const float4*)&As[kk][4 * ty];
      float4 b4 = *(const float4*)&Bs[kk][4 * tx];
      float a[4] = {a4.x, a4.y, a4.z, a4.w};
      float b[4] = {b4.x, b4.y, b4.z, b4.w};
      #pragma unroll
      for (int i = 0; i < 4; ++i)
        #pragma unroll
        for (int j = 0; j < 4; ++j) acc[i][j] = fmaf(a[i], b[j], acc[i][j]);
    }
  }
  float* Pz = p2 + (size_t)blockIdx.z * 40960;
  #pragma unroll
  for (int i = 0; i < 4; ++i) {
    int m = m0 + 4 * ty + i, n = n0 + 4 * tx;
    if (n < N)
      *(float4*)(Pz + (size_t)m * 160 + n) = make_float4(acc[i][0], acc[i][1], acc[i][2], acc[i][3]);
  }
}

// Finish d2: rx = relu(sum_z p2 + b_d2) * LOG2E (f32 for score_final), plus
// 3-way bf16 split (RNE level 0/1; residuals exact by Sterbenz) stored
// in MFMA-B-fragment-friendly [col][k] layout for score_mfma.
__global__ __launch_bounds__(256) void rx_prep(const float* __restrict__ p2,
    const float* __restrict__ bd2, float* __restrict__ rx,
    unsigned short* __restrict__ rx0, unsigned short* __restrict__ rx1,
    unsigned short* __restrict__ rx2) {
  int b = blockIdx.x, t = threadIdx.x;
  if (t >= 160) return;
  float a = bd2[t];
  #pragma unroll
  for (int z = 0; z < 8; ++z) a += p2[(size_t)z * 40960 + b * 160 + t];
  float v = fmaxf(a, 0.f) * LOG2E;
  rx[b * 160 + t] = v;
  int col = b * 10 + (t >> 4), e = t & 15;
  float f0 = bfround(v);
  float d1 = v - f0;            // exact (Sterbenz)
  float f1 = bfround(d1);
  float d2 = d1 - f1;           // exact
  float f2 = bfround(d2);
  rx0[col * 16 + e] = (unsigned short)(__float_as_uint(f0) >> 16);
  rx1[col * 16 + e] = (unsigned short)(__float_as_uint(f1) >> 16);
  rx2[col * 16 + e] = (unsigned short)(__float_as_uint(f2) >> 16);
}

// MFMA scoring: per wave, FOUR 32-column groups (cols quad*128 + {0,32,64,96} + ln),
// TPC item-tiles. logits via v_mfma_f32_32x32x16_bf16; emb split: EXACT truncation
// 3-way (v = t0+t1+t2, zero error); kept products i+j<=2 (dropped <= 2^-24 rel).
// zacc trick: first MFMA of each chain takes loop-invariant C = splat(-SHIFT)
// (MFMA dst may differ from C src) -> no per-tile acc init; arithmetic bitwise
// identical to the round-5 kernel (same C value, same product order).
// C-layout: col = lane&31, row = (reg&3) + 8*(reg>>2) + 4*(lane>>5).
// A/B frag: row/col = lane&31, k = (lane>>5)*8 + i. Pad rows (>=50000) use
// emb = -128 -> x <= -64, never beats a real row (strict > + ascending order).
// No LDS/barriers; one shfl_xor(32) per col at end.
__global__ __launch_bounds__(256) void score_mfma(const float* __restrict__ emb,
    const unsigned short* __restrict__ rx0, const unsigned short* __restrict__ rx1,
    const unsigned short* __restrict__ rx2,
    float* __restrict__ ps, float* __restrict__ pm, int* __restrict__ pa) {
  int t = threadIdx.x;
  int w = t >> 6, l = t & 63;
  int ln = l & 31, hf = l >> 5;
  int quad = blockIdx.x * 4 + w;   // 0..19 column-quad groups (128 cols each)
  int ic = blockIdx.y;             // 0..127 item chunks
  int col0 = quad * 128 + ln;
  bfrag bq0[4], bq1[4], bq2[4];
  #pragma unroll
  for (int q = 0; q < 4; ++q) {
    size_t off = (size_t)(col0 + 32 * q) * 16 + hf * 8;
    bq0[q] = *(const bfrag*)(rx0 + off);
    bq1[q] = *(const bfrag*)(rx1 + off);
    bq2[q] = *(const bfrag*)(rx2 + off);
  }
  f32x16 zacc;
  #pragma unroll
  for (int i = 0; i < 16; ++i) zacc[i] = -SHIFT;
  float s[4], m[4];
  int am[4];
  #pragma unroll
  for (int q = 0; q < 4; ++q) { s[q] = 0.f; m[q] = -3.402823466e38f; am[q] = 0x7FFFFFFF; }
  int ts = ic * TPC, te = ts + TPC;
  if (te > NT) te = NT;
  #pragma unroll 1
  for (int tile = ts; tile < te; ++tile) {
    int r = tile * 32 + ln;
    float4 e0, e1;
    if (r < NITEMS) {
      const float4* p = (const float4*)(emb + (size_t)r * 16 + hf * 8);
      e0 = p[0]; e1 = p[1];
    } else {
      e0 = make_float4(-128.f, -128.f, -128.f, -128.f);
      e1 = e0;
    }
    float ev[8] = {e0.x, e0.y, e0.z, e0.w, e1.x, e1.y, e1.z, e1.w};
    union { bfrag f; unsigned u[4]; } A0, A1, A2;
    #pragma unroll
    for (int j = 0; j < 4; ++j) {
      float v0 = ev[2 * j], v1 = ev[2 * j + 1];
      unsigned u0 = __float_as_uint(v0), u1 = __float_as_uint(v1);
      A0.u[j] = (u0 >> 16) | (u1 & 0xFFFF0000u);
      float r0 = v0 - __uint_as_float(u0 & 0xFFFF0000u);   // exact
      float r1 = v1 - __uint_as_float(u1 & 0xFFFF0000u);   // exact
      unsigned w0 = __float_as_uint(r0), w1 = __float_as_uint(r1);
      A1.u[j] = (w0 >> 16) | (w1 & 0xFFFF0000u);
      float q0 = r0 - __uint_as_float(w0 & 0xFFFF0000u);   // exact, fits bf16
      float q1 = r1 - __uint_as_float(w1 & 0xFFFF0000u);   // exact, fits bf16
      A2.u[j] = (__float_as_uint(q0) >> 16) | (__float_as_uint(q1) & 0xFFFF0000u);
    }
    f32x16 acc[4];
    // product order per chain identical to verified round-5 kernel:
    // A1B1 (from zacc), A2B0, A0B2, A1B0, A0B1, A0B0 -- interleaved across 4 chains
    #pragma unroll
    for (int q = 0; q < 4; ++q)
      acc[q] = __builtin_amdgcn_mfma_f32_32x32x16_bf16(A1.f, bq1[q], zacc, 0, 0, 0);
    #pragma unroll
    for (int q = 0; q < 4; ++q)
      acc[q] = __builtin_amdgcn_mfma_f32_32x32x16_bf16(A2.f, bq0[q], acc[q], 0, 0, 0);
    #pragma unroll
    for (int q = 0; q < 4; ++q)
      acc[q] = __builtin_amdgcn_mfma_f32_32x32x16_bf16(A0.f, bq2[q], acc[q], 0, 0, 0);
    #pragma unroll
    for (int q = 0; q < 4; ++q)
      acc[q] = __builtin_amdgcn_mfma_f32_32x32x16_bf16(A1.f, bq0[q], acc[q], 0, 0, 0);
    #pragma unroll
    for (int q = 0; q < 4; ++q)
      acc[q] = __builtin_amdgcn_mfma_f32_32x32x16_bf16(A0.f, bq1[q], acc[q], 0, 0, 0);
    #pragma unroll
    for (int q = 0; q < 4; ++q)
      acc[q] = __builtin_amdgcn_mfma_f32_32x32x16_bf16(A0.f, bq0[q], acc[q], 0, 0, 0);
    int base = tile * 32 + 4 * hf;
    // reg order g*4+i visits rows ascending -> strict > keeps lowest index on ties
    #pragma unroll
    for (int q = 0; q < 4; ++q) {
      #pragma unroll
      for (int g = 0; g < 4; ++g) {
        #pragma unroll
        for (int i = 0; i < 4; ++i) {
          float x = acc[q][g * 4 + i];
          s[q] += __builtin_amdgcn_exp2f(x);
          if (x > m[q]) { m[q] = x; am[q] = base + 8 * g + i; }
        }
      }
    }
  }
  // lanes (l, l+32) hold the same col, disjoint row sets
  #pragma unroll
  for (int q = 0; q < 4; ++q) {
    s[q] += __shfl_xor(s[q], 32);
    float om = __shfl_xor(m[q], 32);
    int oa = __shfl_xor(am[q], 32);
    if (om > m[q] || (om == m[q] && oa < am[q])) { m[q] = om; am[q] = oa; }
  }
  if (hf == 0) {
    #pragma unroll
    for (int q = 0; q < 4; ++q) {
      int idx = ic * NCOL + col0 + 32 * q;
      ps[idx] = s[q]; pm[idx] = m[q]; pa[idx] = am[q];
    }
  }
}

// Combine chunk partials: S adds (shared fixed shift); argmax; slate prob.
__global__ __launch_bounds__(256) void score_final(const float* __restrict__ psg,
    const float* __restrict__ pmg, const int* __restrict__ pag,
    const float* __restrict__ rx, const float* __restrict__ emb,
    const int* __restrict__ slate, float* __restrict__ out) {
  int tid = blockIdx.x * 256 + threadIdx.x;
  if (tid >= BATCH * 10) return;
  int b = tid / 10, k = tid % 10;
  float S = 0.f, M = -3.402823466e38f;
  int AM = 2147483647;
  for (int c = 0; c < IC; ++c) {
    int idx = c * NCOL + tid;   // col == tid
    S += psg[idx];
    float m2 = pmg[idx];
    int oa = pag[idx];
    bool take = (m2 > M) || (m2 == M && oa < AM);
    AM = take ? oa : AM;
    M = fmaxf(M, m2);
  }
  int it = slate[b * 10 + k];
  const float* er = emb + (size_t)it * 16;
  const float* rr = rx + b * 160 + k * 16;  // pre-scaled by LOG2E
  float xs = -SHIFT;
  #pragma unroll
  for (int e = 0; e < 16; ++e) xs = fmaf(rr[e], er[e], xs);
  out[OUT_RS + b * 10 + k] = (float)AM;
  out[OUT_RR + b * 10 + k] = __builtin_amdgcn_exp2f(xs) / S;
}

extern "C" void kernel_launch(void* const* d_in, const int* in_sizes, int n_in,
                              void* d_out, int out_size, void* d_ws, size_t ws_size,
                              hipStream_t stream) {
  const int* user_repr = (const int*)d_in[0];
  const int* slate = (const int*)d_in[1];
  const float* resp = (const float*)d_in[2];
  const float* eps = (const float*)d_in[3];
  const float* emb = (const float*)d_in[4];
  const float* W_enc = (const float*)d_in[5];
  const float* b_enc = (const float*)d_in[6];
  const float* W_mu = (const float*)d_in[7];
  const float* b_mu = (const float*)d_in[8];
  const float* W_lv = (const float*)d_in[9];
  const float* b_lv = (const float*)d_in[10];
  const float* W_d1 = (const float*)d_in[11];
  const float* b_d1 = (const float*)d_in[12];
  const float* W_d2 = (const float*)d_in[13];
  const float* b_d2 = (const float*)d_in[14];
  float* out = (float*)d_out;
  float* ws = (float*)d_ws;

  float* x    = ws + WS_X;
  float* dz   = ws + WS_DZ;
  float* p2   = ws + WS_P2;
  float* pp   = ws + WS_PP;
  float* part = ws + WS_PART;
  float* ps   = ws + WS_PS;
  float* pmb  = ws + WS_PM;
  int*   pab  = (int*)(ws + WS_PA);
  float* rx   = ws + WS_RX;
  unsigned short* rx0 = (unsigned short*)(ws + WS_RXS0);
  unsigned short* rx1 = (unsigned short*)(ws + WS_RXS1);
  unsigned short* rx2 = (unsigned short*)(ws + WS_RXS2);

  pool_part<<<dim3(64, NPCH), 256, 0, stream>>>(user_repr, emb, pp);
  build_x<<<256, 256, 0, stream>>>(pp, slate, resp, emb, x, dz);
  gemm64<<<dim3(8, 4, 4), 256, 0, stream>>>(x, W_enc, part, 256, 512, 1200, 300);
  mulv_z_kernel<<<256, 128, 0, stream>>>(part, b_enc, W_mu, b_mu, W_lv, b_lv, eps, out, dz);
  gemm64<<<dim3(8, 4, 4), 256, 0, stream>>>(dz, W_d1, part, 256, 512, 1104, 276);
  gemm_d2<<<dim3(3, 4, 8), 256, 0, stream>>>(part, b_d1, W_d2, p2);
  rx_prep<<<256, 256, 0, stream>>>(p2, b_d2, rx, rx0, rx1, rx2);
  score_mfma<<<dim3(5, IC), 256, 0, stream>>>(emb, rx0, rx1, rx2, ps, pmb, pab);
  score_final<<<10, 256, 0, stream>>>(ps, pmb, pab, rx, emb, slate, out);
}

// Round 7
// 273.011 us; speedup vs baseline: 1.0354x; 1.0354x over previous
//
#include <hip/hip_runtime.h>

// Problem constants
#define NITEMS 50000
#define EMBD   16
#define NSLATE 10
#define HIDD   512
#define LATD   64
#define RESPD  1024
#define BATCH  256
#define NPCH   10     // pool chunks: 50000/10 = 5000 items = 1250 int4 per chunk
#define PI4    1250   // int4s per pool chunk
#define BG     4      // batches per pool block (emb row loaded once, used 4x)
#define LOG2E  1.44269504088896340736f
#define SHIFT  64.0f  // fixed log2-domain shift: s = sum exp2(x*log2e - 64)

// MFMA scoring: logits = rx[2560x16] @ emb^T[16x50000] via v_mfma_f32_32x32x16_bf16.
// C=2 col-groups/wave (VGPR ~64), IC=224 chunks -> 2240 blocks (~28+ waves/CU):
// round-6 showed the kernel is STALL-bound (per-SIMD VALU issue ~12%, occ 13%),
// so resident-wave count is the lever, not per-visit instruction count.
#define NCOL   2560   // BATCH*NSLATE output columns
#define NT     1563   // ceil(50000/32) item tiles (last tile has 16 pad rows)
#define IC     224    // item chunks (grid.y)
#define TPC    7      // tiles per chunk: 224*7 = 1568 >= 1563

// d_out layout (float): z_mean[256*64] | z_log_var[256*64] | recon_slate[256*10] | recon_resp[256*10]
#define OUT_ZM 0
#define OUT_ZLV 16384
#define OUT_RS 32768
#define OUT_RR 35328

// ws layout (floats), with time-overlays (all dispatches stream-ordered):
//   [0 .. 589824)        x[307200] + dz[282624]  (build_x -> enc / d1)
//                        OVERLAY p2[8*40960=327680] (gemm_d2 -> rx_prep)
//   [0 .. 573440)        OVERLAY score S-partials ps[224*2560] (score_mfma -> score_final)
//   [573440 .. 578560)   OVERLAY keys[2560 u64] packed (mono(m)<<32 | 2047-tile);
//                        zeroed in rx_prep, atomicMax'd in score_mfma, read by fixup
//   [589824 .. 868352)   pool partials pp [64bg*10c*4wv*68 = 174080 used] (pool_part -> build_x)
//   [589824 .. 1114112)  OVERLAY part[4*131072] (enc->mulv_z, d1->gemm_d2)
//   [1114112 .. 1155072) rx[40960] f32, LOG2E-scaled (rx_prep -> score_final)
//   [1155072 .. 1216512) rx bf16 3-way split rx0/rx1/rx2 [3*40960 ushort]
// total 1216512 floats = 4.87 MB (identical to known-safe footprint)
#define WS_X    0
#define WS_DZ   307200
#define WS_P2   0
#define WS_PS   0
#define WS_KEY  573440
#define WS_PP   589824
#define WS_PART 589824
#define WS_RX   1114112
#define WS_RXS0 1155072
#define WS_RXS1 1175552
#define WS_RXS2 1196032

typedef __attribute__((ext_vector_type(8))) short bfrag;    // 8 bf16 = 4 VGPR (A/B operand)
typedef __attribute__((ext_vector_type(16))) float f32x16;  // C/D operand

// round-to-nearest-even f32 -> bf16, returned as f32 with low mantissa zeroed
__device__ __forceinline__ float bfround(float v) {
  unsigned u = __float_as_uint(v);
  unsigned r = (u + 0x7FFFu + ((u >> 16) & 1u)) & 0xFFFF0000u;
  return __uint_as_float(r);
}

// monotone bijection f32 -> u32 (x < y  <=>  mono(x) < mono(y))
__device__ __forceinline__ unsigned mono32(float f) {
  unsigned u = __float_as_uint(f);
  return (u & 0x80000000u) ? ~u : (u | 0x80000000u);
}

#define FMAX3(a, b, c) fmaxf(fmaxf((a), (b)), (c))

// Pool partials: grid (64 bg, 10 c), BG=4 batches per block. BRANCH-FREE weighted
// accumulate (acc = fmaf(u, e, acc)); emb row loaded once per block, used 4x.
__global__ __launch_bounds__(256) void pool_part(const int* __restrict__ u,
    const float* __restrict__ emb, float* __restrict__ pp) {
  int bg = blockIdx.x, c = blockIdx.y, t = threadIdx.x;
  float acc[BG][17];
  #pragma unroll
  for (int j = 0; j < BG; ++j)
    #pragma unroll
    for (int i = 0; i < 17; ++i) acc[j][i] = 0.0f;
  const int4* ub = (const int4*)u;
  size_t base = (size_t)(bg * BG) * 12500 + (size_t)c * PI4;
  int nBase = c * 5000;
  for (int i4 = t; i4 < PI4; i4 += 256) {
    int4 u0 = ub[base + i4];
    int4 u1 = ub[base + 12500 + i4];
    int4 u2 = ub[base + 25000 + i4];
    int4 u3 = ub[base + 37500 + i4];
    int w[BG][4] = {{u0.x, u0.y, u0.z, u0.w}, {u1.x, u1.y, u1.z, u1.w},
                    {u2.x, u2.y, u2.z, u2.w}, {u3.x, u3.y, u3.z, u3.w}};
    const float4* e4 = (const float4*)(emb + (size_t)(nBase + i4 * 4) * 16);
    #pragma unroll
    for (int it = 0; it < 4; ++it) {
      float4 ea = e4[it * 4 + 0], eb = e4[it * 4 + 1];
      float4 ec = e4[it * 4 + 2], ed = e4[it * 4 + 3];
      #pragma unroll
      for (int j = 0; j < BG; ++j) {
        float wf = (float)w[j][it];
        acc[j][0]  = fmaf(wf, ea.x, acc[j][0]);
        acc[j][1]  = fmaf(wf, ea.y, acc[j][1]);
        acc[j][2]  = fmaf(wf, ea.z, acc[j][2]);
        acc[j][3]  = fmaf(wf, ea.w, acc[j][3]);
        acc[j][4]  = fmaf(wf, eb.x, acc[j][4]);
        acc[j][5]  = fmaf(wf, eb.y, acc[j][5]);
        acc[j][6]  = fmaf(wf, eb.z, acc[j][6]);
        acc[j][7]  = fmaf(wf, eb.w, acc[j][7]);
        acc[j][8]  = fmaf(wf, ec.x, acc[j][8]);
        acc[j][9]  = fmaf(wf, ec.y, acc[j][9]);
        acc[j][10] = fmaf(wf, ec.z, acc[j][10]);
        acc[j][11] = fmaf(wf, ec.w, acc[j][11]);
        acc[j][12] = fmaf(wf, ed.x, acc[j][12]);
        acc[j][13] = fmaf(wf, ed.y, acc[j][13]);
        acc[j][14] = fmaf(wf, ed.z, acc[j][14]);
        acc[j][15] = fmaf(wf, ed.w, acc[j][15]);
        acc[j][16] += wf;
      }
    }
  }
  #pragma unroll
  for (int off = 32; off > 0; off >>= 1) {
    #pragma unroll
    for (int j = 0; j < BG; ++j)
      #pragma unroll
      for (int i = 0; i < 17; ++i) acc[j][i] += __shfl_down(acc[j][i], off);
  }
  int lane = t & 63, wv = t >> 6;
  if (lane == 0) {
    float* dst = pp + (size_t)((bg * NPCH + c) * 4 + wv) * (BG * 17);
    #pragma unroll
    for (int j = 0; j < BG; ++j)
      #pragma unroll
      for (int i = 0; i < 17; ++i) dst[j * 17 + i] = acc[j][i];
  }
}

// Sum 40 wave-partials per b; build x = [slate(160)|user(16)|resp(1024)],
// dz[64:1104] = [user|resp].
__global__ __launch_bounds__(256) void build_x(const float* __restrict__ pp,
    const int* __restrict__ slate, const float* __restrict__ resp,
    const float* __restrict__ emb, float* __restrict__ x, float* __restrict__ dz) {
  __shared__ float fin[17];
  int b = blockIdx.x, t = threadIdx.x;
  if (t < 17) {
    int bg = b >> 2, j = b & 3;
    float a = 0.f;
    const float* p = pp + (size_t)(bg * NPCH * 4) * (BG * 17) + j * 17 + t;
    #pragma unroll
    for (int w = 0; w < NPCH * 4; ++w) a += p[(size_t)w * (BG * 17)];
    fin[t] = a;
  }
  __syncthreads();
  float inv = 1.0f / fin[16];
  if (t < 16) {
    float uv = fin[t] * inv;
    x[b * 1200 + 160 + t] = uv;
    dz[b * 1104 + 64 + t] = uv;
  }
  if (t >= 32 && t < 192) {
    int i = t - 32;
    int k = i >> 4, e = i & 15;
    int it = slate[b * 10 + k];
    x[b * 1200 + i] = emb[(size_t)it * 16 + e];
  }
  for (int i = t; i < 1024; i += 256) {
    float r = resp[b * 1024 + i];
    x[b * 1200 + 176 + i] = r;
    dz[b * 1104 + 80 + i] = r;
  }
}

// Split-K partial GEMM: P[z][M,N] = A[M,ks:ke] @ B[N,ks:ke]^T
__global__ __launch_bounds__(256) void gemm64(const float* __restrict__ A,
    const float* __restrict__ B, float* __restrict__ P, int M, int N, int K, int kChunk) {
  __shared__ float As[16][68];  // As[kk][m]
  __shared__ float Bs[16][68];  // Bs[kk][n]
  int tid = threadIdx.x;
  int m0 = blockIdx.y * 64, n0 = blockIdx.x * 64;
  int ks = blockIdx.z * kChunk;
  int ke = ks + kChunk; if (ke > K) ke = K;
  int sr = tid >> 2;          // 0..63
  int sc = (tid & 3) * 4;     // 0,4,8,12
  int tx = tid & 15, ty = tid >> 4;
  float acc[4][4];
  #pragma unroll
  for (int i = 0; i < 4; ++i)
    #pragma unroll
    for (int j = 0; j < 4; ++j) acc[i][j] = 0.f;
  for (int k0 = ks; k0 < ke; k0 += 16) {
    float4 av = make_float4(0.f, 0.f, 0.f, 0.f);
    float4 bv = make_float4(0.f, 0.f, 0.f, 0.f);
    if (k0 + sc < ke)
      av = *(const float4*)(A + (size_t)(m0 + sr) * K + k0 + sc);
    if (k0 + sc < ke && n0 + sr < N)
      bv = *(const float4*)(B + (size_t)(n0 + sr) * K + k0 + sc);
    __syncthreads();
    As[sc][sr] = av.x; As[sc + 1][sr] = av.y; As[sc + 2][sr] = av.z; As[sc + 3][sr] = av.w;
    Bs[sc][sr] = bv.x; Bs[sc + 1][sr] = bv.y; Bs[sc + 2][sr] = bv.z; Bs[sc + 3][sr] = bv.w;
    __syncthreads();
    #pragma unroll
    for (int kk = 0; kk < 16; ++kk) {
      float4 a4 = *(const float4*)&As[kk][4 * ty];
      float4 b4 = *(const float4*)&Bs[kk][4 * tx];
      float a[4] = {a4.x, a4.y, a4.z, a4.w};
      float b[4] = {b4.x, b4.y, b4.z, b4.w};
      #pragma unroll
      for (int i = 0; i < 4; ++i)
        #pragma unroll
        for (int j = 0; j < 4; ++j) acc[i][j] = fmaf(a[i], b[j], acc[i][j]);
    }
  }
  float* Pz = P + (size_t)blockIdx.z * M * N;
  #pragma unroll
  for (int i = 0; i < 4; ++i) {
    int m = m0 + 4 * ty + i, n = n0 + 4 * tx;
    if (n < N)
      *(float4*)(Pz + (size_t)m * N + n) = make_float4(acc[i][0], acc[i][1], acc[i][2], acc[i][3]);
  }
}

// h = relu(sum_s part[s] + b_enc); z_mean/z_log_var -> out; z -> dz[0:64]
__global__ __launch_bounds__(128) void mulv_z_kernel(const float* __restrict__ part,
    const float* __restrict__ benc,
    const float* __restrict__ Wmu, const float* __restrict__ bmu,
    const float* __restrict__ Wlv, const float* __restrict__ blv,
    const float* __restrict__ eps, float* __restrict__ out, float* __restrict__ dz) {
  __shared__ __align__(16) float hs[512];
  __shared__ float zms[64], zlvs[64];
  int b = blockIdx.x, t = threadIdx.x;
  for (int i = t; i < 512; i += 128) {
    float a = benc[i];
    #pragma unroll
    for (int s = 0; s < 4; ++s) a += part[(size_t)s * 131072 + b * 512 + i];
    hs[i] = fmaxf(a, 0.f);
  }
  __syncthreads();
  const float* Wr = (t < 64) ? (Wmu + (size_t)t * 512) : (Wlv + (size_t)(t - 64) * 512);
  float bias = (t < 64) ? bmu[t] : blv[t - 64];
  const float4* w4 = (const float4*)Wr;
  const float4* h4 = (const float4*)hs;
  float a0 = 0.f, a1 = 0.f, a2 = 0.f, a3 = 0.f;
  #pragma unroll 4
  for (int i = 0; i < 128; ++i) {
    float4 w = w4[i], hv = h4[i];
    a0 = fmaf(w.x, hv.x, a0); a1 = fmaf(w.y, hv.y, a1);
    a2 = fmaf(w.z, hv.z, a2); a3 = fmaf(w.w, hv.w, a3);
  }
  float acc = (a0 + a1) + (a2 + a3) + bias;
  if (t < 64) { out[OUT_ZM + b * 64 + t] = acc; zms[t] = acc; }
  else        { out[OUT_ZLV + b * 64 + (t - 64)] = acc; zlvs[t - 64] = acc; }
  __syncthreads();
  if (t < 64) {
    float zv = fmaf(eps[b * 64 + t], __builtin_amdgcn_exp2f(0.7213475204444817f * zlvs[t]), zms[t]);
    dz[b * 1104 + t] = zv;
  }
}

// d2 split-K GEMM with reduce-on-load: A[m][k] = relu(sum_s part[s][m*512+k] + b_d1[k]),
// P2[z] = A[:, z*64:(z+1)*64] @ W_d2[:, same]^T. Grid (3,4,8). Bias/relu/scale in rx_prep.
__global__ __launch_bounds__(256) void gemm_d2(const float* __restrict__ part,
    const float* __restrict__ bd1, const float* __restrict__ W, float* __restrict__ p2) {
  __shared__ float As[16][68];
  __shared__ float Bs[16][68];
  const int N = 160;
  int tid = threadIdx.x;
  int m0 = blockIdx.y * 64, n0 = blockIdx.x * 64;
  int ks = blockIdx.z * 64, ke = ks + 64;
  int sr = tid >> 2, sc = (tid & 3) * 4;
  int tx = tid & 15, ty = tid >> 4;
  float acc[4][4];
  #pragma unroll
  for (int i = 0; i < 4; ++i)
    #pragma unroll
    for (int j = 0; j < 4; ++j) acc[i][j] = 0.f;
  for (int k0 = ks; k0 < ke; k0 += 16) {
    int col = k0 + sc;
    const float* p = part + (size_t)(m0 + sr) * 512 + col;
    float4 a0 = *(const float4*)(p);
    float4 a1 = *(const float4*)(p + 131072);
    float4 a2 = *(const float4*)(p + 262144);
    float4 a3 = *(const float4*)(p + 393216);
    float4 bb = *(const float4*)(bd1 + col);
    float4 av;
    av.x = fmaxf(a0.x + a1.x + a2.x + a3.x + bb.x, 0.f);
    av.y = fmaxf(a0.y + a1.y + a2.y + a3.y + bb.y, 0.f);
    av.z = fmaxf(a0.z + a1.z + a2.z + a3.z + bb.z, 0.f);
    av.w = fmaxf(a0.w + a1.w + a2.w + a3.w + bb.w, 0.f);
    float4 bv = make_float4(0.f, 0.f, 0.f, 0.f);
    if (n0 + sr < N)
      bv = *(const float4*)(W + (size_t)(n0 + sr) * 512 + col);
    __syncthreads();
    As[sc][sr] = av.x; As[sc + 1][sr] = av.y; As[sc + 2][sr] = av.z; As[sc + 3][sr] = av.w;
    Bs[sc][sr] = bv.x; Bs[sc + 1][sr] = bv.y; Bs[sc + 2][sr] = bv.z; Bs[sc + 3][sr] = bv.w;
    __syncthreads();
    #pragma unroll
    for (int kk = 0; kk < 16; ++kk) {
      float4 a4 = *(const float4*)&As[kk][4 * ty];
      float4 b4 = *(const float4*)&Bs[kk][4 * tx];
      float a[4] = {a4.x, a4.y, a4.z, a4.w};
      float b[4] = {b4.x, b4.y, b4.z, b4.w};
      #pragma unroll
      for (int i = 0; i < 4; ++i)
        #pragma unroll
        for (int j = 0; j < 4; ++j) acc[i][j] = fmaf(a[i], b[j], acc[i][j]);
    }
  }
  float* Pz = p2 + (size_t)blockIdx.z * 40960;
  #pragma unroll
  for (int i = 0; i < 4; ++i) {
    int m = m0 + 4 * ty + i, n = n0 + 4 * tx;
    if (n < N)
      *(float4*)(Pz + (size_t)m * 160 + n) = make_float4(acc[i][0], acc[i][1], acc[i][2], acc[i][3]);
  }
}

// Finish d2: rx = relu(sum_z p2 + b_d2) * LOG2E, 3-way bf16 split, and ZERO the
// per-col argmax keys (2560 u64; blockIdx covers b, t<10 covers the 10 slate cols).
__global__ __launch_bounds__(256) void rx_prep(const float* __restrict__ p2,
    const float* __restrict__ bd2, float* __restrict__ rx,
    unsigned short* __restrict__ rx0, unsigned short* __restrict__ rx1,
    unsigned short* __restrict__ rx2, unsigned long long* __restrict__ keys) {
  int b = blockIdx.x, t = threadIdx.x;
  if (t < 10) keys[b * 10 + t] = 0ULL;
  if (t >= 160) return;
  float a = bd2[t];
  #pragma unroll
  for (int z = 0; z < 8; ++z) a += p2[(size_t)z * 40960 + b * 160 + t];
  float v = fmaxf(a, 0.f) * LOG2E;
  rx[b * 160 + t] = v;
  int col = b * 10 + (t >> 4), e = t & 15;
  float f0 = bfround(v);
  float d1 = v - f0;            // exact (Sterbenz)
  float f1 = bfround(d1);
  float d2 = d1 - f1;           // exact
  float f2 = bfround(d2);
  rx0[col * 16 + e] = (unsigned short)(__float_as_uint(f0) >> 16);
  rx1[col * 16 + e] = (unsigned short)(__float_as_uint(f1) >> 16);
  rx2[col * 16 + e] = (unsigned short)(__float_as_uint(f2) >> 16);
}

// MFMA scoring: per wave TWO 32-col groups, TPC tiles/chunk, IC=224 chunks.
// Epilogue per tile per chain: 16 exp2-sums + fmax TREE (tile max only, no per-logit
// argmax) + tile-index cndmask. Global (max, tile) combined via per-col packed
// atomicMax key = mono(m)<<32 | (2047 - tile): max-m wins, ties -> lowest tile
// (= lowest item index; tiles ascend). Load-filter skips losing atomics.
// S partials -> ps (plain writes, deterministic). Item index recovered by
// argmax_fix re-running the ONE winning tile bit-exactly.
__global__ __launch_bounds__(256) void score_mfma(const float* __restrict__ emb,
    const unsigned short* __restrict__ rx0, const unsigned short* __restrict__ rx1,
    const unsigned short* __restrict__ rx2,
    float* __restrict__ ps, unsigned long long* __restrict__ keys) {
  int t = threadIdx.x;
  int w = t >> 6, l = t & 63;
  int ln = l & 31, hf = l >> 5;
  int pair = blockIdx.x * 4 + w;   // 0..39 column-pair groups
  int ic = blockIdx.y;             // 0..223 item chunks
  int colA = pair * 64 + ln;       // 0..2559
  int colB = colA + 32;
  size_t offA = (size_t)colA * 16 + hf * 8;
  size_t offB = (size_t)colB * 16 + hf * 8;
  bfrag bA0 = *(const bfrag*)(rx0 + offA);
  bfrag bA1 = *(const bfrag*)(rx1 + offA);
  bfrag bA2 = *(const bfrag*)(rx2 + offA);
  bfrag bB0 = *(const bfrag*)(rx0 + offB);
  bfrag bB1 = *(const bfrag*)(rx1 + offB);
  bfrag bB2 = *(const bfrag*)(rx2 + offB);
  float sA = 0.f, sB = 0.f;
  float mA = -3.402823466e38f, mB = -3.402823466e38f;
  int tlA = 0, tlB = 0;
  int ts = ic * TPC, te = ts + TPC;
  if (te > NT) te = NT;
  #pragma unroll 1
  for (int tile = ts; tile < te; ++tile) {
    int r = tile * 32 + ln;
    float4 e0, e1;
    if (r < NITEMS) {
      const float4* p = (const float4*)(emb + (size_t)r * 16 + hf * 8);
      e0 = p[0]; e1 = p[1];
    } else {
      e0 = make_float4(-128.f, -128.f, -128.f, -128.f);
      e1 = e0;
    }
    float ev[8] = {e0.x, e0.y, e0.z, e0.w, e1.x, e1.y, e1.z, e1.w};
    union { bfrag f; unsigned u[4]; } A0, A1, A2;
    #pragma unroll
    for (int j = 0; j < 4; ++j) {
      float v0 = ev[2 * j], v1 = ev[2 * j + 1];
      unsigned u0 = __float_as_uint(v0), u1 = __float_as_uint(v1);
      A0.u[j] = (u0 >> 16) | (u1 & 0xFFFF0000u);
      float r0 = v0 - __uint_as_float(u0 & 0xFFFF0000u);   // exact
      float r1 = v1 - __uint_as_float(u1 & 0xFFFF0000u);   // exact
      unsigned w0 = __float_as_uint(r0), w1 = __float_as_uint(r1);
      A1.u[j] = (w0 >> 16) | (w1 & 0xFFFF0000u);
      float q0 = r0 - __uint_as_float(w0 & 0xFFFF0000u);   // exact, fits bf16
      float q1 = r1 - __uint_as_float(w1 & 0xFFFF0000u);   // exact, fits bf16
      A2.u[j] = (__float_as_uint(q0) >> 16) | (__float_as_uint(q1) & 0xFFFF0000u);
    }
    f32x16 accA, accB;
    #pragma unroll
    for (int i = 0; i < 16; ++i) { accA[i] = -SHIFT; accB[i] = -SHIFT; }
    // product order per chain identical to verified round-5 kernel
    accA = __builtin_amdgcn_mfma_f32_32x32x16_bf16(A1.f, bA1, accA, 0, 0, 0);
    accB = __builtin_amdgcn_mfma_f32_32x32x16_bf16(A1.f, bB1, accB, 0, 0, 0);
    accA = __builtin_amdgcn_mfma_f32_32x32x16_bf16(A2.f, bA0, accA, 0, 0, 0);
    accB = __builtin_amdgcn_mfma_f32_32x32x16_bf16(A2.f, bB0, accB, 0, 0, 0);
    accA = __builtin_amdgcn_mfma_f32_32x32x16_bf16(A0.f, bA2, accA, 0, 0, 0);
    accB = __builtin_amdgcn_mfma_f32_32x32x16_bf16(A0.f, bB2, accB, 0, 0, 0);
    accA = __builtin_amdgcn_mfma_f32_32x32x16_bf16(A1.f, bA0, accA, 0, 0, 0);
    accB = __builtin_amdgcn_mfma_f32_32x32x16_bf16(A1.f, bB0, accB, 0, 0, 0);
    accA = __builtin_amdgcn_mfma_f32_32x32x16_bf16(A0.f, bA1, accA, 0, 0, 0);
    accB = __builtin_amdgcn_mfma_f32_32x32x16_bf16(A0.f, bB1, accB, 0, 0, 0);
    accA = __builtin_amdgcn_mfma_f32_32x32x16_bf16(A0.f, bA0, accA, 0, 0, 0);
    accB = __builtin_amdgcn_mfma_f32_32x32x16_bf16(A0.f, bB0, accB, 0, 0, 0);
    float tmA, tmB;
    {
      float f1 = FMAX3(accA[0], accA[1], accA[2]);
      float f2 = FMAX3(accA[3], accA[4], accA[5]);
      float f3 = FMAX3(accA[6], accA[7], accA[8]);
      float f4 = FMAX3(accA[9], accA[10], accA[11]);
      float f5 = FMAX3(accA[12], accA[13], accA[14]);
      float g1 = FMAX3(f1, f2, accA[15]);
      float g2 = fmaxf(f3, f4);
      tmA = FMAX3(g1, g2, f5);
    }
    {
      float f1 = FMAX3(accB[0], accB[1], accB[2]);
      float f2 = FMAX3(accB[3], accB[4], accB[5]);
      float f3 = FMAX3(accB[6], accB[7], accB[8]);
      float f4 = FMAX3(accB[9], accB[10], accB[11]);
      float f5 = FMAX3(accB[12], accB[13], accB[14]);
      float g1 = FMAX3(f1, f2, accB[15]);
      float g2 = fmaxf(f3, f4);
      tmB = FMAX3(g1, g2, f5);
    }
    if (tmA > mA) { mA = tmA; tlA = tile; }   // strict > : lowest tile on ties
    if (tmB > mB) { mB = tmB; tlB = tile; }
    #pragma unroll
    for (int i = 0; i < 16; ++i) {
      sA += __builtin_amdgcn_exp2f(accA[i]);
      sB += __builtin_amdgcn_exp2f(accB[i]);
    }
  }
  // lanes (l, l+32) hold the same col, disjoint row sets
  sA += __shfl_xor(sA, 32);
  sB += __shfl_xor(sB, 32);
  {
    float om = __shfl_xor(mA, 32); int ot = __shfl_xor(tlA, 32);
    if (om > mA || (om == mA && ot < tlA)) { mA = om; tlA = ot; }
  }
  {
    float om = __shfl_xor(mB, 32); int ot = __shfl_xor(tlB, 32);
    if (om > mB || (om == mB && ot < tlB)) { mB = om; tlB = ot; }
  }
  if (hf == 0) {
    ps[ic * NCOL + colA] = sA;
    ps[ic * NCOL + colB] = sB;
    unsigned long long kA = ((unsigned long long)mono32(mA) << 32) | (unsigned)(2047 - tlA);
    unsigned long long kB = ((unsigned long long)mono32(mB) << 32) | (unsigned)(2047 - tlB);
    if (kA > keys[colA]) atomicMax(&keys[colA], kA);   // load-filter then atomic
    if (kB > keys[colB]) atomicMax(&keys[colB], kB);
  }
}

// Argmax fixup: grid (80 col-groups, 8 residue classes), 1 wave each. For each col,
// decode (mono_m, tile) from its key; waves with tile%8==k re-run that ONE tile
// through the bit-identical split+MFMA chain and find the lowest row whose value
// bit-matches mono_m. Writes recon_slate.
__global__ __launch_bounds__(64) void argmax_fix(const unsigned long long* __restrict__ keys,
    const unsigned short* __restrict__ rx0, const unsigned short* __restrict__ rx1,
    const unsigned short* __restrict__ rx2, const float* __restrict__ emb,
    float* __restrict__ out) {
  int l = threadIdx.x, ln = l & 31, hf = l >> 5;
  int g = blockIdx.x, k = blockIdx.y;
  int col = g * 32 + ln;
  unsigned long long key = keys[col];
  unsigned um = (unsigned)(key >> 32);
  int tl = 2047 - (int)(key & 0xFFFFFFFFu);
  size_t off = (size_t)col * 16 + hf * 8;
  bfrag b0 = *(const bfrag*)(rx0 + off);
  bfrag b1 = *(const bfrag*)(rx1 + off);
  bfrag b2 = *(const bfrag*)(rx2 + off);
  bool done = ((tl & 7) != k);
  while (true) {
    int tsel = done ? 0x7FFFFFFF : tl;
    #pragma unroll
    for (int o = 32; o > 0; o >>= 1) tsel = min(tsel, __shfl_xor(tsel, o));
    if (tsel == 0x7FFFFFFF) break;
    int r = tsel * 32 + ln;
    float4 e0, e1;
    if (r < NITEMS) {
      const float4* p = (const float4*)(emb + (size_t)r * 16 + hf * 8);
      e0 = p[0]; e1 = p[1];
    } else {
      e0 = make_float4(-128.f, -128.f, -128.f, -128.f);
      e1 = e0;
    }
    float ev[8] = {e0.x, e0.y, e0.z, e0.w, e1.x, e1.y, e1.z, e1.w};
    union { bfrag f; unsigned u[4]; } A0, A1, A2;
    #pragma unroll
    for (int j = 0; j < 4; ++j) {
      float v0 = ev[2 * j], v1 = ev[2 * j + 1];
      unsigned u0 = __float_as_uint(v0), u1 = __float_as_uint(v1);
      A0.u[j] = (u0 >> 16) | (u1 & 0xFFFF0000u);
      float r0 = v0 - __uint_as_float(u0 & 0xFFFF0000u);
      float r1 = v1 - __uint_as_float(u1 & 0xFFFF0000u);
      unsigned w0 = __float_as_uint(r0), w1 = __float_as_uint(r1);
      A1.u[j] = (w0 >> 16) | (w1 & 0xFFFF0000u);
      float q0 = r0 - __uint_as_float(w0 & 0xFFFF0000u);
      float q1 = r1 - __uint_as_float(w1 & 0xFFFF0000u);
      A2.u[j] = (__float_as_uint(q0) >> 16) | (__float_as_uint(q1) & 0xFFFF0000u);
    }
    f32x16 acc;
    #pragma unroll
    for (int i = 0; i < 16; ++i) acc[i] = -SHIFT;
    acc = __builtin_amdgcn_mfma_f32_32x32x16_bf16(A1.f, b1, acc, 0, 0, 0);
    acc = __builtin_amdgcn_mfma_f32_32x32x16_bf16(A2.f, b0, acc, 0, 0, 0);
    acc = __builtin_amdgcn_mfma_f32_32x32x16_bf16(A0.f, b2, acc, 0, 0, 0);
    acc = __builtin_amdgcn_mfma_f32_32x32x16_bf16(A1.f, b0, acc, 0, 0, 0);
    acc = __builtin_amdgcn_mfma_f32_32x32x16_bf16(A0.f, b1, acc, 0, 0, 0);
    acc = __builtin_amdgcn_mfma_f32_32x32x16_bf16(A0.f, b0, acc, 0, 0, 0);
    if (!done && tl == tsel) {
      int best = 0x7FFFFFFF;
      #pragma unroll
      for (int g2 = 0; g2 < 4; ++g2)
        #pragma unroll
        for (int i = 0; i < 4; ++i) {
          float x = acc[g2 * 4 + i];
          int row = 8 * g2 + 4 * hf + i;
          if (mono32(x) == um) best = min(best, tsel * 32 + row);
        }
      int ob = __shfl_xor(best, 32);
      best = min(best, ob);
      if (hf == 0) out[OUT_RS + col] = (float)best;
      done = true;
    }
  }
}

// Combine chunk S-partials (shared fixed shift) + slate prob.
__global__ __launch_bounds__(256) void score_final(const float* __restrict__ psg,
    const float* __restrict__ rx, const float* __restrict__ emb,
    const int* __restrict__ slate, float* __restrict__ out) {
  int tid = blockIdx.x * 256 + threadIdx.x;
  if (tid >= BATCH * 10) return;
  int b = tid / 10, k = tid % 10;
  float S = 0.f;
  for (int c = 0; c < IC; ++c) S += psg[c * NCOL + tid];   // col == tid
  int it = slate[b * 10 + k];
  const float* er = emb + (size_t)it * 16;
  const float* rr = rx + b * 160 + k * 16;  // pre-scaled by LOG2E
  float xs = -SHIFT;
  #pragma unroll
  for (int e = 0; e < 16; ++e) xs = fmaf(rr[e], er[e], xs);
  out[OUT_RR + b * 10 + k] = __builtin_amdgcn_exp2f(xs) / S;
}

extern "C" void kernel_launch(void* const* d_in, const int* in_sizes, int n_in,
                              void* d_out, int out_size, void* d_ws, size_t ws_size,
                              hipStream_t stream) {
  const int* user_repr = (const int*)d_in[0];
  const int* slate = (const int*)d_in[1];
  const float* resp = (const float*)d_in[2];
  const float* eps = (const float*)d_in[3];
  const float* emb = (const float*)d_in[4];
  const float* W_enc = (const float*)d_in[5];
  const float* b_enc = (const float*)d_in[6];
  const float* W_mu = (const float*)d_in[7];
  const float* b_mu = (const float*)d_in[8];
  const float* W_lv = (const float*)d_in[9];
  const float* b_lv = (const float*)d_in[10];
  const float* W_d1 = (const float*)d_in[11];
  const float* b_d1 = (const float*)d_in[12];
  const float* W_d2 = (const float*)d_in[13];
  const float* b_d2 = (const float*)d_in[14];
  float* out = (float*)d_out;
  float* ws = (float*)d_ws;

  float* x    = ws + WS_X;
  float* dz   = ws + WS_DZ;
  float* p2   = ws + WS_P2;
  float* pp   = ws + WS_PP;
  float* part = ws + WS_PART;
  float* ps   = ws + WS_PS;
  unsigned long long* keys = (unsigned long long*)(ws + WS_KEY);
  float* rx   = ws + WS_RX;
  unsigned short* rx0 = (unsigned short*)(ws + WS_RXS0);
  unsigned short* rx1 = (unsigned short*)(ws + WS_RXS1);
  unsigned short* rx2 = (unsigned short*)(ws + WS_RXS2);

  pool_part<<<dim3(64, NPCH), 256, 0, stream>>>(user_repr, emb, pp);
  build_x<<<256, 256, 0, stream>>>(pp, slate, resp, emb, x, dz);
  gemm64<<<dim3(8, 4, 4), 256, 0, stream>>>(x, W_enc, part, 256, 512, 1200, 300);
  mulv_z_kernel<<<256, 128, 0, stream>>>(part, b_enc, W_mu, b_mu, W_lv, b_lv, eps, out, dz);
  gemm64<<<dim3(8, 4, 4), 256, 0, stream>>>(dz, W_d1, part, 256, 512, 1104, 276);
  gemm_d2<<<dim3(3, 4, 8), 256, 0, stream>>>(part, b_d1, W_d2, p2);
  rx_prep<<<256, 256, 0, stream>>>(p2, b_d2, rx, rx0, rx1, rx2, keys);
  score_mfma<<<dim3(10, IC), 256, 0, stream>>>(emb, rx0, rx1, rx2, ps, keys);
  argmax_fix<<<dim3(80, 8), 64, 0, stream>>>(keys, rx0, rx1, rx2, emb, out);
  score_final<<<10, 256, 0, stream>>>(ps, rx, emb, slate, out);
}

// Round 8
// 268.156 us; speedup vs baseline: 1.0541x; 1.0181x over previous
//
#include <hip/hip_runtime.h>

// Problem constants
#define NITEMS 50000
#define EMBD   16
#define NSLATE 10
#define HIDD   512
#define LATD   64
#define RESPD  1024
#define BATCH  256
#define NPCH   25    // pool chunks: 50000/25 = 2000 items = 500 int4 per chunk
#define PI4    500   // int4s per pool chunk
#define BG     4     // batches per pool block (emb row loaded once, used 4x)
#define LOG2E  1.44269504088896340736f
#define SHIFT  64.0f  // fixed log2-domain shift: s = sum exp2(x*log2e - 64)

// MFMA scoring: logits = rx[2560x16] @ emb^T[16x50000] via v_mfma_f32_32x32x16_bf16.
// C=2 col-groups/wave (VGPR ~64), IC=224 chunks -> 2240 blocks (~28+ waves/CU).
#define NCOL   2560   // BATCH*NSLATE output columns
#define NT     1563   // ceil(50000/32) item tiles (last tile has 16 pad rows)
#define IC     224    // item chunks (grid.y)
#define TPC    7      // tiles per chunk: 224*7 = 1568 >= 1563

// d_out layout (float): z_mean[256*64] | z_log_var[256*64] | recon_slate[256*10] | recon_resp[256*10]
#define OUT_ZM 0
#define OUT_ZLV 16384
#define OUT_RS 32768
#define OUT_RR 35328

// ws layout (floats), with time-overlays (all dispatches stream-ordered):
//   [0 .. 589824)        x[307200] + dz[282624]  (build_x -> enc / d1)
//                        OVERLAY p2[8*40960=327680] (gemm_d2 -> rx_prep)
//   [0 .. 573440)        OVERLAY score S-partials ps[224*2560] (score_mfma -> score_final)
//   [573440 .. 578560)   OVERLAY keys[2560 u64] packed (mono(m)<<32 | 2047-tile);
//                        zeroed in rx_prep, atomicMax'd in score_mfma, read by fixup
//   [589824 .. 1114112)  pool partials pp [64bg*25c*4wv*68 = 435200 used] (pool_part -> build_x)
//                        OVERLAY part[4*131072] (enc->mulv_z, d1->gemm_d2)
//   [1114112 .. 1155072) rx[40960] f32, LOG2E-scaled (rx_prep -> score_final)
//   [1155072 .. 1216512) rx bf16 3-way split rx0/rx1/rx2 [3*40960 ushort]
// total 1216512 floats = 4.87 MB (identical to known-safe footprint)
#define WS_X    0
#define WS_DZ   307200
#define WS_P2   0
#define WS_PS   0
#define WS_KEY  573440
#define WS_PP   589824
#define WS_PART 589824
#define WS_RX   1114112
#define WS_RXS0 1155072
#define WS_RXS1 1175552
#define WS_RXS2 1196032

typedef __attribute__((ext_vector_type(8))) short bfrag;    // 8 bf16 = 4 VGPR (A/B operand)
typedef __attribute__((ext_vector_type(16))) float f32x16;  // C/D operand

// round-to-nearest-even f32 -> bf16, returned as f32 with low mantissa zeroed
__device__ __forceinline__ float bfround(float v) {
  unsigned u = __float_as_uint(v);
  unsigned r = (u + 0x7FFFu + ((u >> 16) & 1u)) & 0xFFFF0000u;
  return __uint_as_float(r);
}

// monotone bijection f32 -> u32 (x < y  <=>  mono(x) < mono(y))
__device__ __forceinline__ unsigned mono32(float f) {
  unsigned u = __float_as_uint(f);
  return (u & 0x80000000u) ? ~u : (u | 0x80000000u);
}

#define FMAX3(a, b, c) fmaxf(fmaxf((a), (b)), (c))

// Pool partials: grid (64 bg, 25 c), BG=4 batches per block -> 1600 blocks
// (6.25/CU; VGPR-84 residency cap of 16 waves/CU stays filled -- round-7 showed
// 640 blocks left only ~5 waves/CU resident and the kernel latency-bound at
// VALU 10%/HBM 10%). BRANCH-FREE weighted accumulate (acc = fmaf(u, e, acc));
// emb row loaded once per block, used 4x. Per-wave partial [4][17] -> pp.
__global__ __launch_bounds__(256) void pool_part(const int* __restrict__ u,
    const float* __restrict__ emb, float* __restrict__ pp) {
  int bg = blockIdx.x, c = blockIdx.y, t = threadIdx.x;
  float acc[BG][17];
  #pragma unroll
  for (int j = 0; j < BG; ++j)
    #pragma unroll
    for (int i = 0; i < 17; ++i) acc[j][i] = 0.0f;
  const int4* ub = (const int4*)u;
  size_t base = (size_t)(bg * BG) * 12500 + (size_t)c * PI4;
  int nBase = c * 2000;
  for (int i4 = t; i4 < PI4; i4 += 256) {
    int4 u0 = ub[base + i4];
    int4 u1 = ub[base + 12500 + i4];
    int4 u2 = ub[base + 25000 + i4];
    int4 u3 = ub[base + 37500 + i4];
    int w[BG][4] = {{u0.x, u0.y, u0.z, u0.w}, {u1.x, u1.y, u1.z, u1.w},
                    {u2.x, u2.y, u2.z, u2.w}, {u3.x, u3.y, u3.z, u3.w}};
    const float4* e4 = (const float4*)(emb + (size_t)(nBase + i4 * 4) * 16);
    #pragma unroll
    for (int it = 0; it < 4; ++it) {
      float4 ea = e4[it * 4 + 0], eb = e4[it * 4 + 1];
      float4 ec = e4[it * 4 + 2], ed = e4[it * 4 + 3];
      #pragma unroll
      for (int j = 0; j < BG; ++j) {
        float wf = (float)w[j][it];
        acc[j][0]  = fmaf(wf, ea.x, acc[j][0]);
        acc[j][1]  = fmaf(wf, ea.y, acc[j][1]);
        acc[j][2]  = fmaf(wf, ea.z, acc[j][2]);
        acc[j][3]  = fmaf(wf, ea.w, acc[j][3]);
        acc[j][4]  = fmaf(wf, eb.x, acc[j][4]);
        acc[j][5]  = fmaf(wf, eb.y, acc[j][5]);
        acc[j][6]  = fmaf(wf, eb.z, acc[j][6]);
        acc[j][7]  = fmaf(wf, eb.w, acc[j][7]);
        acc[j][8]  = fmaf(wf, ec.x, acc[j][8]);
        acc[j][9]  = fmaf(wf, ec.y, acc[j][9]);
        acc[j][10] = fmaf(wf, ec.z, acc[j][10]);
        acc[j][11] = fmaf(wf, ec.w, acc[j][11]);
        acc[j][12] = fmaf(wf, ed.x, acc[j][12]);
        acc[j][13] = fmaf(wf, ed.y, acc[j][13]);
        acc[j][14] = fmaf(wf, ed.z, acc[j][14]);
        acc[j][15] = fmaf(wf, ed.w, acc[j][15]);
        acc[j][16] += wf;
      }
    }
  }
  #pragma unroll
  for (int off = 32; off > 0; off >>= 1) {
    #pragma unroll
    for (int j = 0; j < BG; ++j)
      #pragma unroll
      for (int i = 0; i < 17; ++i) acc[j][i] += __shfl_down(acc[j][i], off);
  }
  int lane = t & 63, wv = t >> 6;
  if (lane == 0) {
    float* dst = pp + (size_t)((bg * NPCH + c) * 4 + wv) * (BG * 17);
    #pragma unroll
    for (int j = 0; j < BG; ++j)
      #pragma unroll
      for (int i = 0; i < 17; ++i) dst[j * 17 + i] = acc[j][i];
  }
}

// Sum 100 wave-partials per b; build x = [slate(160)|user(16)|resp(1024)],
// dz[64:1104] = [user|resp].
__global__ __launch_bounds__(256) void build_x(const float* __restrict__ pp,
    const int* __restrict__ slate, const float* __restrict__ resp,
    const float* __restrict__ emb, float* __restrict__ x, float* __restrict__ dz) {
  __shared__ float fin[17];
  int b = blockIdx.x, t = threadIdx.x;
  if (t < 17) {
    int bg = b >> 2, j = b & 3;
    float a = 0.f;
    const float* p = pp + (size_t)(bg * NPCH * 4) * (BG * 17) + j * 17 + t;
    #pragma unroll
    for (int w = 0; w < NPCH * 4; ++w) a += p[(size_t)w * (BG * 17)];
    fin[t] = a;
  }
  __syncthreads();
  float inv = 1.0f / fin[16];
  if (t < 16) {
    float uv = fin[t] * inv;
    x[b * 1200 + 160 + t] = uv;
    dz[b * 1104 + 64 + t] = uv;
  }
  if (t >= 32 && t < 192) {
    int i = t - 32;
    int k = i >> 4, e = i & 15;
    int it = slate[b * 10 + k];
    x[b * 1200 + i] = emb[(size_t)it * 16 + e];
  }
  for (int i = t; i < 1024; i += 256) {
    float r = resp[b * 1024 + i];
    x[b * 1200 + 176 + i] = r;
    dz[b * 1104 + 80 + i] = r;
  }
}

// Split-K partial GEMM: P[z][M,N] = A[M,ks:ke] @ B[N,ks:ke]^T
__global__ __launch_bounds__(256) void gemm64(const float* __restrict__ A,
    const float* __restrict__ B, float* __restrict__ P, int M, int N, int K, int kChunk) {
  __shared__ float As[16][68];  // As[kk][m]
  __shared__ float Bs[16][68];  // Bs[kk][n]
  int tid = threadIdx.x;
  int m0 = blockIdx.y * 64, n0 = blockIdx.x * 64;
  int ks = blockIdx.z * kChunk;
  int ke = ks + kChunk; if (ke > K) ke = K;
  int sr = tid >> 2;          // 0..63
  int sc = (tid & 3) * 4;     // 0,4,8,12
  int tx = tid & 15, ty = tid >> 4;
  float acc[4][4];
  #pragma unroll
  for (int i = 0; i < 4; ++i)
    #pragma unroll
    for (int j = 0; j < 4; ++j) acc[i][j] = 0.f;
  for (int k0 = ks; k0 < ke; k0 += 16) {
    float4 av = make_float4(0.f, 0.f, 0.f, 0.f);
    float4 bv = make_float4(0.f, 0.f, 0.f, 0.f);
    if (k0 + sc < ke)
      av = *(const float4*)(A + (size_t)(m0 + sr) * K + k0 + sc);
    if (k0 + sc < ke && n0 + sr < N)
      bv = *(const float4*)(B + (size_t)(n0 + sr) * K + k0 + sc);
    __syncthreads();
    As[sc][sr] = av.x; As[sc + 1][sr] = av.y; As[sc + 2][sr] = av.z; As[sc + 3][sr] = av.w;
    Bs[sc][sr] = bv.x; Bs[sc + 1][sr] = bv.y; Bs[sc + 2][sr] = bv.z; Bs[sc + 3][sr] = bv.w;
    __syncthreads();
    #pragma unroll
    for (int kk = 0; kk < 16; ++kk) {
      float4 a4 = *(const float4*)&As[kk][4 * ty];
      float4 b4 = *(const float4*)&Bs[kk][4 * tx];
      float a[4] = {a4.x, a4.y, a4.z, a4.w};
      float b[4] = {b4.x, b4.y, b4.z, b4.w};
      #pragma unroll
      for (int i = 0; i < 4; ++i)
        #pragma unroll
        for (int j = 0; j < 4; ++j) acc[i][j] = fmaf(a[i], b[j], acc[i][j]);
    }
  }
  float* Pz = P + (size_t)blockIdx.z * M * N;
  #pragma unroll
  for (int i = 0; i < 4; ++i) {
    int m = m0 + 4 * ty + i, n = n0 + 4 * tx;
    if (n < N)
      *(float4*)(Pz + (size_t)m * N + n) = make_float4(acc[i][0], acc[i][1], acc[i][2], acc[i][3]);
  }
}

// h = relu(sum_s part[s] + b_enc); z_mean/z_log_var -> out; z -> dz[0:64]
__global__ __launch_bounds__(128) void mulv_z_kernel(const float* __restrict__ part,
    const float* __restrict__ benc,
    const float* __restrict__ Wmu, const float* __restrict__ bmu,
    const float* __restrict__ Wlv, const float* __restrict__ blv,
    const float* __restrict__ eps, float* __restrict__ out, float* __restrict__ dz) {
  __shared__ __align__(16) float hs[512];
  __shared__ float zms[64], zlvs[64];
  int b = blockIdx.x, t = threadIdx.x;
  for (int i = t; i < 512; i += 128) {
    float a = benc[i];
    #pragma unroll
    for (int s = 0; s < 4; ++s) a += part[(size_t)s * 131072 + b * 512 + i];
    hs[i] = fmaxf(a, 0.f);
  }
  __syncthreads();
  const float* Wr = (t < 64) ? (Wmu + (size_t)t * 512) : (Wlv + (size_t)(t - 64) * 512);
  float bias = (t < 64) ? bmu[t] : blv[t - 64];
  const float4* w4 = (const float4*)Wr;
  const float4* h4 = (const float4*)hs;
  float a0 = 0.f, a1 = 0.f, a2 = 0.f, a3 = 0.f;
  #pragma unroll 4
  for (int i = 0; i < 128; ++i) {
    float4 w = w4[i], hv = h4[i];
    a0 = fmaf(w.x, hv.x, a0); a1 = fmaf(w.y, hv.y, a1);
    a2 = fmaf(w.z, hv.z, a2); a3 = fmaf(w.w, hv.w, a3);
  }
  float acc = (a0 + a1) + (a2 + a3) + bias;
  if (t < 64) { out[OUT_ZM + b * 64 + t] = acc; zms[t] = acc; }
  else        { out[OUT_ZLV + b * 64 + (t - 64)] = acc; zlvs[t - 64] = acc; }
  __syncthreads();
  if (t < 64) {
    float zv = fmaf(eps[b * 64 + t], __builtin_amdgcn_exp2f(0.7213475204444817f * zlvs[t]), zms[t]);
    dz[b * 1104 + t] = zv;
  }
}

// d2 split-K GEMM with reduce-on-load: A[m][k] = relu(sum_s part[s][m*512+k] + b_d1[k]),
// P2[z] = A[:, z*64:(z+1)*64] @ W_d2[:, same]^T. Grid (3,4,8). Bias/relu/scale in rx_prep.
__global__ __launch_bounds__(256) void gemm_d2(const float* __restrict__ part,
    const float* __restrict__ bd1, const float* __restrict__ W, float* __restrict__ p2) {
  __shared__ float As[16][68];
  __shared__ float Bs[16][68];
  const int N = 160;
  int tid = threadIdx.x;
  int m0 = blockIdx.y * 64, n0 = blockIdx.x * 64;
  int ks = blockIdx.z * 64, ke = ks + 64;
  int sr = tid >> 2, sc = (tid & 3) * 4;
  int tx = tid & 15, ty = tid >> 4;
  float acc[4][4];
  #pragma unroll
  for (int i = 0; i < 4; ++i)
    #pragma unroll
    for (int j = 0; j < 4; ++j) acc[i][j] = 0.f;
  for (int k0 = ks; k0 < ke; k0 += 16) {
    int col = k0 + sc;
    const float* p = part + (size_t)(m0 + sr) * 512 + col;
    float4 a0 = *(const float4*)(p);
    float4 a1 = *(const float4*)(p + 131072);
    float4 a2 = *(const float4*)(p + 262144);
    float4 a3 = *(const float4*)(p + 393216);
    float4 bb = *(const float4*)(bd1 + col);
    float4 av;
    av.x = fmaxf(a0.x + a1.x + a2.x + a3.x + bb.x, 0.f);
    av.y = fmaxf(a0.y + a1.y + a2.y + a3.y + bb.y, 0.f);
    av.z = fmaxf(a0.z + a1.z + a2.z + a3.z + bb.z, 0.f);
    av.w = fmaxf(a0.w + a1.w + a2.w + a3.w + bb.w, 0.f);
    float4 bv = make_float4(0.f, 0.f, 0.f, 0.f);
    if (n0 + sr < N)
      bv = *(const float4*)(W + (size_t)(n0 + sr) * 512 + col);
    __syncthreads();
    As[sc][sr] = av.x; As[sc + 1][sr] = av.y; As[sc + 2][sr] = av.z; As[sc + 3][sr] = av.w;
    Bs[sc][sr] = bv.x; Bs[sc + 1][sr] = bv.y; Bs[sc + 2][sr] = bv.z; Bs[sc + 3][sr] = bv.w;
    __syncthreads();
    #pragma unroll
    for (int kk = 0; kk < 16; ++kk) {
      float4 a4 = *(const float4*)&As[kk][4 * ty];
      float4 b4 = *(const float4*)&Bs[kk][4 * tx];
      float a[4] = {a4.x, a4.y, a4.z, a4.w};
      float b[4] = {b4.x, b4.y, b4.z, b4.w};
      #pragma unroll
      for (int i = 0; i < 4; ++i)
        #pragma unroll
        for (int j = 0; j < 4; ++j) acc[i][j] = fmaf(a[i], b[j], acc[i][j]);
    }
  }
  float* Pz = p2 + (size_t)blockIdx.z * 40960;
  #pragma unroll
  for (int i = 0; i < 4; ++i) {
    int m = m0 + 4 * ty + i, n = n0 + 4 * tx;
    if (n < N)
      *(float4*)(Pz + (size_t)m * 160 + n) = make_float4(acc[i][0], acc[i][1], acc[i][2], acc[i][3]);
  }
}

// Finish d2: rx = relu(sum_z p2 + b_d2) * LOG2E, 3-way bf16 split, and ZERO the
// per-col argmax keys (2560 u64; blockIdx covers b, t<10 covers the 10 slate cols).
__global__ __launch_bounds__(256) void rx_prep(const float* __restrict__ p2,
    const float* __restrict__ bd2, float* __restrict__ rx,
    unsigned short* __restrict__ rx0, unsigned short* __restrict__ rx1,
    unsigned short* __restrict__ rx2, unsigned long long* __restrict__ keys) {
  int b = blockIdx.x, t = threadIdx.x;
  if (t < 10) keys[b * 10 + t] = 0ULL;
  if (t >= 160) return;
  float a = bd2[t];
  #pragma unroll
  for (int z = 0; z < 8; ++z) a += p2[(size_t)z * 40960 + b * 160 + t];
  float v = fmaxf(a, 0.f) * LOG2E;
  rx[b * 160 + t] = v;
  int col = b * 10 + (t >> 4), e = t & 15;
  float f0 = bfround(v);
  float d1 = v - f0;            // exact (Sterbenz)
  float f1 = bfround(d1);
  float d2 = d1 - f1;           // exact
  float f2 = bfround(d2);
  rx0[col * 16 + e] = (unsigned short)(__float_as_uint(f0) >> 16);
  rx1[col * 16 + e] = (unsigned short)(__float_as_uint(f1) >> 16);
  rx2[col * 16 + e] = (unsigned short)(__float_as_uint(f2) >> 16);
}

// MFMA scoring: per wave TWO 32-col groups, TPC tiles/chunk, IC=224 chunks.
// Per tile per chain: 16 exp2-sums + fmax tree (tile max) + tile-index select.
// Global (max, tile) via per-col packed atomicMax key = mono(m)<<32 | (2047-tile)
// (max-m wins, ties -> lowest tile = lowest item). Load-filter skips losing
// atomics. S partials -> ps. Item index recovered by argmax_fix (bit-exact rerun).
__global__ __launch_bounds__(256) void score_mfma(const float* __restrict__ emb,
    const unsigned short* __restrict__ rx0, const unsigned short* __restrict__ rx1,
    const unsigned short* __restrict__ rx2,
    float* __restrict__ ps, unsigned long long* __restrict__ keys) {
  int t = threadIdx.x;
  int w = t >> 6, l = t & 63;
  int ln = l & 31, hf = l >> 5;
  int pair = blockIdx.x * 4 + w;   // 0..39 column-pair groups
  int ic = blockIdx.y;             // 0..223 item chunks
  int colA = pair * 64 + ln;       // 0..2559
  int colB = colA + 32;
  size_t offA = (size_t)colA * 16 + hf * 8;
  size_t offB = (size_t)colB * 16 + hf * 8;
  bfrag bA0 = *(const bfrag*)(rx0 + offA);
  bfrag bA1 = *(const bfrag*)(rx1 + offA);
  bfrag bA2 = *(const bfrag*)(rx2 + offA);
  bfrag bB0 = *(const bfrag*)(rx0 + offB);
  bfrag bB1 = *(const bfrag*)(rx1 + offB);
  bfrag bB2 = *(const bfrag*)(rx2 + offB);
  float sA = 0.f, sB = 0.f;
  float mA = -3.402823466e38f, mB = -3.402823466e38f;
  int tlA = 0, tlB = 0;
  int ts = ic * TPC, te = ts + TPC;
  if (te > NT) te = NT;
  #pragma unroll 1
  for (int tile = ts; tile < te; ++tile) {
    int r = tile * 32 + ln;
    float4 e0, e1;
    if (r < NITEMS) {
      const float4* p = (const float4*)(emb + (size_t)r * 16 + hf * 8);
      e0 = p[0]; e1 = p[1];
    } else {
      e0 = make_float4(-128.f, -128.f, -128.f, -128.f);
      e1 = e0;
    }
    float ev[8] = {e0.x, e0.y, e0.z, e0.w, e1.x, e1.y, e1.z, e1.w};
    union { bfrag f; unsigned u[4]; } A0, A1, A2;
    #pragma unroll
    for (int j = 0; j < 4; ++j) {
      float v0 = ev[2 * j], v1 = ev[2 * j + 1];
      unsigned u0 = __float_as_uint(v0), u1 = __float_as_uint(v1);
      A0.u[j] = (u0 >> 16) | (u1 & 0xFFFF0000u);
      float r0 = v0 - __uint_as_float(u0 & 0xFFFF0000u);   // exact
      float r1 = v1 - __uint_as_float(u1 & 0xFFFF0000u);   // exact
      unsigned w0 = __float_as_uint(r0), w1 = __float_as_uint(r1);
      A1.u[j] = (w0 >> 16) | (w1 & 0xFFFF0000u);
      float q0 = r0 - __uint_as_float(w0 & 0xFFFF0000u);   // exact, fits bf16
      float q1 = r1 - __uint_as_float(w1 & 0xFFFF0000u);   // exact, fits bf16
      A2.u[j] = (__float_as_uint(q0) >> 16) | (__float_as_uint(q1) & 0xFFFF0000u);
    }
    f32x16 accA, accB;
    #pragma unroll
    for (int i = 0; i < 16; ++i) { accA[i] = -SHIFT; accB[i] = -SHIFT; }
    // product order per chain identical to verified round-5 kernel
    accA = __builtin_amdgcn_mfma_f32_32x32x16_bf16(A1.f, bA1, accA, 0, 0, 0);
    accB = __builtin_amdgcn_mfma_f32_32x32x16_bf16(A1.f, bB1, accB, 0, 0, 0);
    accA = __builtin_amdgcn_mfma_f32_32x32x16_bf16(A2.f, bA0, accA, 0, 0, 0);
    accB = __builtin_amdgcn_mfma_f32_32x32x16_bf16(A2.f, bB0, accB, 0, 0, 0);
    accA = __builtin_amdgcn_mfma_f32_32x32x16_bf16(A0.f, bA2, accA, 0, 0, 0);
    accB = __builtin_amdgcn_mfma_f32_32x32x16_bf16(A0.f, bB2, accB, 0, 0, 0);
    accA = __builtin_amdgcn_mfma_f32_32x32x16_bf16(A1.f, bA0, accA, 0, 0, 0);
    accB = __builtin_amdgcn_mfma_f32_32x32x16_bf16(A1.f, bB0, accB, 0, 0, 0);
    accA = __builtin_amdgcn_mfma_f32_32x32x16_bf16(A0.f, bA1, accA, 0, 0, 0);
    accB = __builtin_amdgcn_mfma_f32_32x32x16_bf16(A0.f, bB1, accB, 0, 0, 0);
    accA = __builtin_amdgcn_mfma_f32_32x32x16_bf16(A0.f, bA0, accA, 0, 0, 0);
    accB = __builtin_amdgcn_mfma_f32_32x32x16_bf16(A0.f, bB0, accB, 0, 0, 0);
    float tmA, tmB;
    {
      float f1 = FMAX3(accA[0], accA[1], accA[2]);
      float f2 = FMAX3(accA[3], accA[4], accA[5]);
      float f3 = FMAX3(accA[6], accA[7], accA[8]);
      float f4 = FMAX3(accA[9], accA[10], accA[11]);
      float f5 = FMAX3(accA[12], accA[13], accA[14]);
      float g1 = FMAX3(f1, f2, accA[15]);
      float g2 = fmaxf(f3, f4);
      tmA = FMAX3(g1, g2, f5);
    }
    {
      float f1 = FMAX3(accB[0], accB[1], accB[2]);
      float f2 = FMAX3(accB[3], accB[4], accB[5]);
      float f3 = FMAX3(accB[6], accB[7], accB[8]);
      float f4 = FMAX3(accB[9], accB[10], accB[11]);
      float f5 = FMAX3(accB[12], accB[13], accB[14]);
      float g1 = FMAX3(f1, f2, accB[15]);
      float g2 = fmaxf(f3, f4);
      tmB = FMAX3(g1, g2, f5);
    }
    if (tmA > mA) { mA = tmA; tlA = tile; }   // strict > : lowest tile on ties
    if (tmB > mB) { mB = tmB; tlB = tile; }
    #pragma unroll
    for (int i = 0; i < 16; ++i) {
      sA += __builtin_amdgcn_exp2f(accA[i]);
      sB += __builtin_amdgcn_exp2f(accB[i]);
    }
  }
  // lanes (l, l+32) hold the same col, disjoint row sets
  sA += __shfl_xor(sA, 32);
  sB += __shfl_xor(sB, 32);
  {
    float om = __shfl_xor(mA, 32); int ot = __shfl_xor(tlA, 32);
    if (om > mA || (om == mA && ot < tlA)) { mA = om; tlA = ot; }
  }
  {
    float om = __shfl_xor(mB, 32); int ot = __shfl_xor(tlB, 32);
    if (om > mB || (om == mB && ot < tlB)) { mB = om; tlB = ot; }
  }
  if (hf == 0) {
    ps[ic * NCOL + colA] = sA;
    ps[ic * NCOL + colB] = sB;
    unsigned long long kA = ((unsigned long long)mono32(mA) << 32) | (unsigned)(2047 - tlA);
    unsigned long long kB = ((unsigned long long)mono32(mB) << 32) | (unsigned)(2047 - tlB);
    if (kA > keys[colA]) atomicMax(&keys[colA], kA);   // load-filter then atomic
    if (kB > keys[colB]) atomicMax(&keys[colB], kB);
  }
}

// Argmax fixup: grid (80 col-groups, 8 residue classes), 1 wave each. For each col,
// decode (mono_m, tile) from its key; waves with tile%8==k re-run that ONE tile
// through the bit-identical split+MFMA chain and find the lowest row whose value
// bit-matches mono_m. Writes recon_slate.
__global__ __launch_bounds__(64) void argmax_fix(const unsigned long long* __restrict__ keys,
    const unsigned short* __restrict__ rx0, const unsigned short* __restrict__ rx1,
    const unsigned short* __restrict__ rx2, const float* __restrict__ emb,
    float* __restrict__ out) {
  int l = threadIdx.x, ln = l & 31, hf = l >> 5;
  int g = blockIdx.x, k = blockIdx.y;
  int col = g * 32 + ln;
  unsigned long long key = keys[col];
  unsigned um = (unsigned)(key >> 32);
  int tl = 2047 - (int)(key & 0xFFFFFFFFu);
  size_t off = (size_t)col * 16 + hf * 8;
  bfrag b0 = *(const bfrag*)(rx0 + off);
  bfrag b1 = *(const bfrag*)(rx1 + off);
  bfrag b2 = *(const bfrag*)(rx2 + off);
  bool done = ((tl & 7) != k);
  while (true) {
    int tsel = done ? 0x7FFFFFFF : tl;
    #pragma unroll
    for (int o = 32; o > 0; o >>= 1) tsel = min(tsel, __shfl_xor(tsel, o));
    if (tsel == 0x7FFFFFFF) break;
    int r = tsel * 32 + ln;
    float4 e0, e1;
    if (r < NITEMS) {
      const float4* p = (const float4*)(emb + (size_t)r * 16 + hf * 8);
      e0 = p[0]; e1 = p[1];
    } else {
      e0 = make_float4(-128.f, -128.f, -128.f, -128.f);
      e1 = e0;
    }
    float ev[8] = {e0.x, e0.y, e0.z, e0.w, e1.x, e1.y, e1.z, e1.w};
    union { bfrag f; unsigned u[4]; } A0, A1, A2;
    #pragma unroll
    for (int j = 0; j < 4; ++j) {
      float v0 = ev[2 * j], v1 = ev[2 * j + 1];
      unsigned u0 = __float_as_uint(v0), u1 = __float_as_uint(v1);
      A0.u[j] = (u0 >> 16) | (u1 & 0xFFFF0000u);
      float r0 = v0 - __uint_as_float(u0 & 0xFFFF0000u);
      float r1 = v1 - __uint_as_float(u1 & 0xFFFF0000u);
      unsigned w0 = __float_as_uint(r0), w1 = __float_as_uint(r1);
      A1.u[j] = (w0 >> 16) | (w1 & 0xFFFF0000u);
      float q0 = r0 - __uint_as_float(w0 & 0xFFFF0000u);
      float q1 = r1 - __uint_as_float(w1 & 0xFFFF0000u);
      A2.u[j] = (__float_as_uint(q0) >> 16) | (__float_as_uint(q1) & 0xFFFF0000u);
    }
    f32x16 acc;
    #pragma unroll
    for (int i = 0; i < 16; ++i) acc[i] = -SHIFT;
    acc = __builtin_amdgcn_mfma_f32_32x32x16_bf16(A1.f, b1, acc, 0, 0, 0);
    acc = __builtin_amdgcn_mfma_f32_32x32x16_bf16(A2.f, b0, acc, 0, 0, 0);
    acc = __builtin_amdgcn_mfma_f32_32x32x16_bf16(A0.f, b2, acc, 0, 0, 0);
    acc = __builtin_amdgcn_mfma_f32_32x32x16_bf16(A1.f, b0, acc, 0, 0, 0);
    acc = __builtin_amdgcn_mfma_f32_32x32x16_bf16(A0.f, b1, acc, 0, 0, 0);
    acc = __builtin_amdgcn_mfma_f32_32x32x16_bf16(A0.f, b0, acc, 0, 0, 0);
    if (!done && tl == tsel) {
      int best = 0x7FFFFFFF;
      #pragma unroll
      for (int g2 = 0; g2 < 4; ++g2)
        #pragma unroll
        for (int i = 0; i < 4; ++i) {
          float x = acc[g2 * 4 + i];
          int row = 8 * g2 + 4 * hf + i;
          if (mono32(x) == um) best = min(best, tsel * 32 + row);
        }
      int ob = __shfl_xor(best, 32);
      best = min(best, ob);
      if (hf == 0) out[OUT_RS + col] = (float)best;
      done = true;
    }
  }
}

// Combine chunk S-partials (shared fixed shift) + slate prob.
__global__ __launch_bounds__(256) void score_final(const float* __restrict__ psg,
    const float* __restrict__ rx, const float* __restrict__ emb,
    const int* __restrict__ slate, float* __restrict__ out) {
  int tid = blockIdx.x * 256 + threadIdx.x;
  if (tid >= BATCH * 10) return;
  int b = tid / 10, k = tid % 10;
  float S = 0.f;
  for (int c = 0; c < IC; ++c) S += psg[c * NCOL + tid];   // col == tid
  int it = slate[b * 10 + k];
  const float* er = emb + (size_t)it * 16;
  const float* rr = rx + b * 160 + k * 16;  // pre-scaled by LOG2E
  float xs = -SHIFT;
  #pragma unroll
  for (int e = 0; e < 16; ++e) xs = fmaf(rr[e], er[e], xs);
  out[OUT_RR + b * 10 + k] = __builtin_amdgcn_exp2f(xs) / S;
}

extern "C" void kernel_launch(void* const* d_in, const int* in_sizes, int n_in,
                              void* d_out, int out_size, void* d_ws, size_t ws_size,
                              hipStream_t stream) {
  const int* user_repr = (const int*)d_in[0];
  const int* slate = (const int*)d_in[1];
  const float* resp = (const float*)d_in[2];
  const float* eps = (const float*)d_in[3];
  const float* emb = (const float*)d_in[4];
  const float* W_enc = (const float*)d_in[5];
  const float* b_enc = (const float*)d_in[6];
  const float* W_mu = (const float*)d_in[7];
  const float* b_mu = (const float*)d_in[8];
  const float* W_lv = (const float*)d_in[9];
  const float* b_lv = (const float*)d_in[10];
  const float* W_d1 = (const float*)d_in[11];
  const float* b_d1 = (const float*)d_in[12];
  const float* W_d2 = (const float*)d_in[13];
  const float* b_d2 = (const float*)d_in[14];
  float* out = (float*)d_out;
  float* ws = (float*)d_ws;

  float* x    = ws + WS_X;
  float* dz   = ws + WS_DZ;
  float* p2   = ws + WS_P2;
  float* pp   = ws + WS_PP;
  float* part = ws + WS_PART;
  float* ps   = ws + WS_PS;
  unsigned long long* keys = (unsigned long long*)(ws + WS_KEY);
  float* rx   = ws + WS_RX;
  unsigned short* rx0 = (unsigned short*)(ws + WS_RXS0);
  unsigned short* rx1 = (unsigned short*)(ws + WS_RXS1);
  unsigned short* rx2 = (unsigned short*)(ws + WS_RXS2);

  pool_part<<<dim3(64, NPCH), 256, 0, stream>>>(user_repr, emb, pp);
  build_x<<<256, 256, 0, stream>>>(pp, slate, resp, emb, x, dz);
  gemm64<<<dim3(8, 4, 4), 256, 0, stream>>>(x, W_enc, part, 256, 512, 1200, 300);
  mulv_z_kernel<<<256, 128, 0, stream>>>(part, b_enc, W_mu, b_mu, W_lv, b_lv, eps, out, dz);
  gemm64<<<dim3(8, 4, 4), 256, 0, stream>>>(dz, W_d1, part, 256, 512, 1104, 276);
  gemm_d2<<<dim3(3, 4, 8), 256, 0, stream>>>(part, b_d1, W_d2, p2);
  rx_prep<<<256, 256, 0, stream>>>(p2, b_d2, rx, rx0, rx1, rx2, keys);
  score_mfma<<<dim3(10, IC), 256, 0, stream>>>(emb, rx0, rx1, rx2, ps, keys);
  argmax_fix<<<dim3(80, 8), 64, 0, stream>>>(keys, rx0, rx1, rx2, emb, out);
  score_final<<<10, 256, 0, stream>>>(ps, rx, emb, slate, out);
}

// Round 9
// 263.730 us; speedup vs baseline: 1.0718x; 1.0168x over previous
//
#include <hip/hip_runtime.h>

// Problem constants
#define NITEMS 50000
#define EMBD   16
#define NSLATE 10
#define HIDD   512
#define LATD   64
#define RESPD  1024
#define BATCH  256
#define KCH    120   // pool k-chunks: 3125 ksteps (=50000/16) split 5x27 + 115x26
#define LOG2E  1.44269504088896340736f
#define SHIFT  64.0f  // fixed log2-domain shift: s = sum exp2(x*log2e - 64)

// MFMA scoring: logits = rx[2560x16] @ emb^T[16x50000] via v_mfma_f32_32x32x16_bf16.
// C=2 col-groups/wave (VGPR ~64), IC=224 chunks -> 2240 blocks.
#define NCOL   2560   // BATCH*NSLATE output columns
#define NT     1563   // ceil(50000/32) item tiles (last tile has 16 pad rows)
#define IC     224    // item chunks (grid.y)
#define TPC    7      // tiles per chunk: 224*7 = 1568 >= 1563

// d_out layout (float): z_mean[256*64] | z_log_var[256*64] | recon_slate[256*10] | recon_resp[256*10]
#define OUT_ZM 0
#define OUT_ZLV 16384
#define OUT_RS 32768
#define OUT_RR 35328

// ws layout (floats), with time-overlays (all dispatches stream-ordered):
//   [0 .. 589824)        x[307200] + dz[282624]  (build_x -> enc / d1)
//                        OVERLAY p2[8*40960=327680] (gemm_d2 -> rx_prep)
//   [0 .. 573440)        OVERLAY score S-partials ps[224*2560] (score_mfma -> score_final)
//   [573440 .. 578560)   OVERLAY keys[2560 u64] packed (mono(m)<<32 | 2047-tile);
//                        zeroed in rx_prep, atomicMax'd in score_mfma, read by fixup
//   [589824 .. 1114112)  pool partials pp [120kc*256*17 = 522240 used] (pool_mfma -> build_x)
//                        OVERLAY part[4*131072] (enc->mulv_z, d1->gemm_d2)
//   [1114112 .. 1155072) rx[40960] f32, LOG2E-scaled (rx_prep -> score_final)
//   [1155072 .. 1216512) rx bf16 3-way split rx0/rx1/rx2 [3*40960 ushort]
// total 1216512 floats = 4.87 MB (identical to known-safe footprint)
#define WS_X    0
#define WS_DZ   307200
#define WS_P2   0
#define WS_PS   0
#define WS_KEY  573440
#define WS_PP   589824
#define WS_PART 589824
#define WS_RX   1114112
#define WS_RXS0 1155072
#define WS_RXS1 1175552
#define WS_RXS2 1196032

typedef __attribute__((ext_vector_type(8))) short bfrag;    // 8 bf16 = 4 VGPR (A/B operand)
typedef __attribute__((ext_vector_type(16))) float f32x16;  // C/D operand

// round-to-nearest-even f32 -> bf16, returned as f32 with low mantissa zeroed
__device__ __forceinline__ float bfround(float v) {
  unsigned u = __float_as_uint(v);
  unsigned r = (u + 0x7FFFu + ((u >> 16) & 1u)) & 0xFFFF0000u;
  return __uint_as_float(r);
}

// monotone bijection f32 -> u32 (x < y  <=>  mono(x) < mono(y))
__device__ __forceinline__ unsigned mono32(float f) {
  unsigned u = __float_as_uint(f);
  return (u & 0x80000000u) ? ~u : (u | 0x80000000u);
}

#define FMAX3(a, b, c) fmaxf(fmaxf((a), (b)), (c))

// MFMA pooling: user[256][17] = U[256x50000] @ [emb | 1] via v_mfma_f32_32x32x16_bf16.
// Round 3-8 post-mortem: three structurally different scalar pools (branchy gather,
// branch-free fmaf, high-occupancy) ALL converge to 47-58us with every pipe <20%
// busy -- the scalar-gather shape pins the 51.2MB u-stream at ~1 TB/s. This kernel
// restates the pool as a K-streaming GEMM: U is EXACT in bf16 (values 0/1), emb
// uses the verified exact truncation 3-way split (all 3 product terms kept -> only
// fp32-accumulation rounding, same class as before). B col16 = 1.0 (count, exact
// fp32 integer <= 50000). A-frag row=lane&31 (batch), k=(lane>>5)*8+i; B-frag
// col=lane&31 (emb dim / count), same k. C col=lane&31, row=(reg&3)+8*(reg>>2)
// +4*(lane>>5). 50000 = 3125x16 ksteps exactly (no tail); K split into 120
// balanced chunks (5x27+115x26); grid (2 row-halves, 120), 4 waves/block, wave
// handles row-tile rt = half*4+wave. Partials [kc][256][17] -> pp.
__global__ __launch_bounds__(256) void pool_mfma(const int* __restrict__ u,
    const float* __restrict__ emb, float* __restrict__ pp) {
  int t = threadIdx.x;
  int w = t >> 6, l = t & 63;
  int ln = l & 31, hf = l >> 5;
  int rt = blockIdx.x * 4 + w;     // 0..7 row tile (32 batches each)
  int kc = blockIdx.y;             // 0..119 k-chunks
  int row = rt * 32 + ln;
  int ks = kc * 26 + min(kc, 5);
  int ke = ks + 26 + (kc < 5 ? 1 : 0);
  const int* uRow = u + (size_t)row * NITEMS + hf * 8;
  f32x16 acc;
  #pragma unroll
  for (int i = 0; i < 16; ++i) acc[i] = 0.f;
  #pragma unroll 1
  for (int k0 = ks; k0 < ke; ++k0) {
    // A: U[row][k0*16 + hf*8 + i], i=0..7 -- 0/1 exact in bf16
    const int4* ap = (const int4*)(uRow + k0 * 16);
    int4 a0 = ap[0], a1 = ap[1];
    union { bfrag f; unsigned ui[4]; } A;
    A.ui[0] = (a0.x ? 0x3F80u : 0u) | (a0.y ? 0x3F800000u : 0u);
    A.ui[1] = (a0.z ? 0x3F80u : 0u) | (a0.w ? 0x3F800000u : 0u);
    A.ui[2] = (a1.x ? 0x3F80u : 0u) | (a1.y ? 0x3F800000u : 0u);
    A.ui[3] = (a1.z ? 0x3F80u : 0u) | (a1.w ? 0x3F800000u : 0u);
    // B: embX[k][col], col=ln: cols 0..15 = emb dims (exact 3-way trunc split),
    // col 16 = 1.0 in B0 (count), cols 17..31 = 0.
    union { bfrag f; unsigned ui[4]; } B0, B1, B2;
    if (ln < 16) {
      const float* ep = emb + (size_t)(k0 * 16 + hf * 8) * 16 + ln;
      #pragma unroll
      for (int j = 0; j < 4; ++j) {
        float v0 = ep[(2 * j) * 16], v1 = ep[(2 * j + 1) * 16];
        unsigned u0 = __float_as_uint(v0), u1 = __float_as_uint(v1);
        B0.ui[j] = (u0 >> 16) | (u1 & 0xFFFF0000u);
        float r0 = v0 - __uint_as_float(u0 & 0xFFFF0000u);   // exact
        float r1 = v1 - __uint_as_float(u1 & 0xFFFF0000u);   // exact
        unsigned w0 = __float_as_uint(r0), w1 = __float_as_uint(r1);
        B1.ui[j] = (w0 >> 16) | (w1 & 0xFFFF0000u);
        float q0 = r0 - __uint_as_float(w0 & 0xFFFF0000u);   // exact, fits bf16
        float q1 = r1 - __uint_as_float(w1 & 0xFFFF0000u);   // exact, fits bf16
        B2.ui[j] = (__float_as_uint(q0) >> 16) | (__float_as_uint(q1) & 0xFFFF0000u);
      }
    } else {
      unsigned c0 = (ln == 16) ? 0x3F803F80u : 0u;
      #pragma unroll
      for (int j = 0; j < 4; ++j) { B0.ui[j] = c0; B1.ui[j] = 0u; B2.ui[j] = 0u; }
    }
    // all 3 terms kept: v = t0+t1+t2 exactly; smallest first
    acc = __builtin_amdgcn_mfma_f32_32x32x16_bf16(A.f, B2.f, acc, 0, 0, 0);
    acc = __builtin_amdgcn_mfma_f32_32x32x16_bf16(A.f, B1.f, acc, 0, 0, 0);
    acc = __builtin_amdgcn_mfma_f32_32x32x16_bf16(A.f, B0.f, acc, 0, 0, 0);
  }
  if (ln < 17) {
    float* dst = pp + (size_t)kc * 4352 + (size_t)(rt * 32) * 17 + ln;
    #pragma unroll
    for (int g = 0; g < 4; ++g)
      #pragma unroll
      for (int q = 0; q < 4; ++q) {
        int r = q + 8 * g + 4 * hf;
        dst[r * 17] = acc[g * 4 + q];
      }
  }
}

// Sum 120 k-chunk partials per b; build x = [slate(160)|user(16)|resp(1024)],
// dz[64:1104] = [user|resp].
__global__ __launch_bounds__(256) void build_x(const float* __restrict__ pp,
    const int* __restrict__ slate, const float* __restrict__ resp,
    const float* __restrict__ emb, float* __restrict__ x, float* __restrict__ dz) {
  __shared__ float fin[17];
  int b = blockIdx.x, t = threadIdx.x;
  if (t < 17) {
    float a = 0.f;
    const float* p = pp + (size_t)b * 17 + t;
    #pragma unroll 8
    for (int kc = 0; kc < KCH; ++kc) a += p[(size_t)kc * 4352];
    fin[t] = a;
  }
  __syncthreads();
  float inv = 1.0f / fin[16];
  if (t < 16) {
    float uv = fin[t] * inv;
    x[b * 1200 + 160 + t] = uv;
    dz[b * 1104 + 64 + t] = uv;
  }
  if (t >= 32 && t < 192) {
    int i = t - 32;
    int k = i >> 4, e = i & 15;
    int it = slate[b * 10 + k];
    x[b * 1200 + i] = emb[(size_t)it * 16 + e];
  }
  for (int i = t; i < 1024; i += 256) {
    float r = resp[b * 1024 + i];
    x[b * 1200 + 176 + i] = r;
    dz[b * 1104 + 80 + i] = r;
  }
}

// Split-K partial GEMM: P[z][M,N] = A[M,ks:ke] @ B[N,ks:ke]^T
__global__ __launch_bounds__(256) void gemm64(const float* __restrict__ A,
    const float* __restrict__ B, float* __restrict__ P, int M, int N, int K, int kChunk) {
  __shared__ float As[16][68];  // As[kk][m]
  __shared__ float Bs[16][68];  // Bs[kk][n]
  int tid = threadIdx.x;
  int m0 = blockIdx.y * 64, n0 = blockIdx.x * 64;
  int ks = blockIdx.z * kChunk;
  int ke = ks + kChunk; if (ke > K) ke = K;
  int sr = tid >> 2;          // 0..63
  int sc = (tid & 3) * 4;     // 0,4,8,12
  int tx = tid & 15, ty = tid >> 4;
  float acc[4][4];
  #pragma unroll
  for (int i = 0; i < 4; ++i)
    #pragma unroll
    for (int j = 0; j < 4; ++j) acc[i][j] = 0.f;
  for (int k0 = ks; k0 < ke; k0 += 16) {
    float4 av = make_float4(0.f, 0.f, 0.f, 0.f);
    float4 bv = make_float4(0.f, 0.f, 0.f, 0.f);
    if (k0 + sc < ke)
      av = *(const float4*)(A + (size_t)(m0 + sr) * K + k0 + sc);
    if (k0 + sc < ke && n0 + sr < N)
      bv = *(const float4*)(B + (size_t)(n0 + sr) * K + k0 + sc);
    __syncthreads();
    As[sc][sr] = av.x; As[sc + 1][sr] = av.y; As[sc + 2][sr] = av.z; As[sc + 3][sr] = av.w;
    Bs[sc][sr] = bv.x; Bs[sc + 1][sr] = bv.y; Bs[sc + 2][sr] = bv.z; Bs[sc + 3][sr] = bv.w;
    __syncthreads();
    #pragma unroll
    for (int kk = 0; kk < 16; ++kk) {
      float4 a4 = *(const float4*)&As[kk][4 * ty];
      float4 b4 = *(const float4*)&Bs[kk][4 * tx];
      float a[4] = {a4.x, a4.y, a4.z, a4.w};
      float b[4] = {b4.x, b4.y, b4.z, b4.w};
      #pragma unroll
      for (int i = 0; i < 4; ++i)
        #pragma unroll
        for (int j = 0; j < 4; ++j) acc[i][j] = fmaf(a[i], b[j], acc[i][j]);
    }
  }
  float* Pz = P + (size_t)blockIdx.z * M * N;
  #pragma unroll
  for (int i = 0; i < 4; ++i) {
    int m = m0 + 4 * ty + i, n = n0 + 4 * tx;
    if (n < N)
      *(float4*)(Pz + (size_t)m * N + n) = make_float4(acc[i][0], acc[i][1], acc[i][2], acc[i][3]);
  }
}

// h = relu(sum_s part[s] + b_enc); z_mean/z_log_var -> out; z -> dz[0:64]
__global__ __launch_bounds__(128) void mulv_z_kernel(const float* __restrict__ part,
    const float* __restrict__ benc,
    const float* __restrict__ Wmu, const float* __restrict__ bmu,
    const float* __restrict__ Wlv, const float* __restrict__ blv,
    const float* __restrict__ eps, float* __restrict__ out, float* __restrict__ dz) {
  __shared__ __align__(16) float hs[512];
  __shared__ float zms[64], zlvs[64];
  int b = blockIdx.x, t = threadIdx.x;
  for (int i = t; i < 512; i += 128) {
    float a = benc[i];
    #pragma unroll
    for (int s = 0; s < 4; ++s) a += part[(size_t)s * 131072 + b * 512 + i];
    hs[i] = fmaxf(a, 0.f);
  }
  __syncthreads();
  const float* Wr = (t < 64) ? (Wmu + (size_t)t * 512) : (Wlv + (size_t)(t - 64) * 512);
  float bias = (t < 64) ? bmu[t] : blv[t - 64];
  const float4* w4 = (const float4*)Wr;
  const float4* h4 = (const float4*)hs;
  float a0 = 0.f, a1 = 0.f, a2 = 0.f, a3 = 0.f;
  #pragma unroll 4
  for (int i = 0; i < 128; ++i) {
    float4 w = w4[i], hv = h4[i];
    a0 = fmaf(w.x, hv.x, a0); a1 = fmaf(w.y, hv.y, a1);
    a2 = fmaf(w.z, hv.z, a2); a3 = fmaf(w.w, hv.w, a3);
  }
  float acc = (a0 + a1) + (a2 + a3) + bias;
  if (t < 64) { out[OUT_ZM + b * 64 + t] = acc; zms[t] = acc; }
  else        { out[OUT_ZLV + b * 64 + (t - 64)] = acc; zlvs[t - 64] = acc; }
  __syncthreads();
  if (t < 64) {
    float zv = fmaf(eps[b * 64 + t], __builtin_amdgcn_exp2f(0.7213475204444817f * zlvs[t]), zms[t]);
    dz[b * 1104 + t] = zv;
  }
}

// d2 split-K GEMM with reduce-on-load: A[m][k] = relu(sum_s part[s][m*512+k] + b_d1[k]),
// P2[z] = A[:, z*64:(z+1)*64] @ W_d2[:, same]^T. Grid (3,4,8). Bias/relu/scale in rx_prep.
__global__ __launch_bounds__(256) void gemm_d2(const float* __restrict__ part,
    const float* __restrict__ bd1, const float* __restrict__ W, float* __restrict__ p2) {
  __shared__ float As[16][68];
  __shared__ float Bs[16][68];
  const int N = 160;
  int tid = threadIdx.x;
  int m0 = blockIdx.y * 64, n0 = blockIdx.x * 64;
  int ks = blockIdx.z * 64, ke = ks + 64;
  int sr = tid >> 2, sc = (tid & 3) * 4;
  int tx = tid & 15, ty = tid >> 4;
  float acc[4][4];
  #pragma unroll
  for (int i = 0; i < 4; ++i)
    #pragma unroll
    for (int j = 0; j < 4; ++j) acc[i][j] = 0.f;
  for (int k0 = ks; k0 < ke; k0 += 16) {
    int col = k0 + sc;
    const float* p = part + (size_t)(m0 + sr) * 512 + col;
    float4 a0 = *(const float4*)(p);
    float4 a1 = *(const float4*)(p + 131072);
    float4 a2 = *(const float4*)(p + 262144);
    float4 a3 = *(const float4*)(p + 393216);
    float4 bb = *(const float4*)(bd1 + col);
    float4 av;
    av.x = fmaxf(a0.x + a1.x + a2.x + a3.x + bb.x, 0.f);
    av.y = fmaxf(a0.y + a1.y + a2.y + a3.y + bb.y, 0.f);
    av.z = fmaxf(a0.z + a1.z + a2.z + a3.z + bb.z, 0.f);
    av.w = fmaxf(a0.w + a1.w + a2.w + a3.w + bb.w, 0.f);
    float4 bv = make_float4(0.f, 0.f, 0.f, 0.f);
    if (n0 + sr < N)
      bv = *(const float4*)(W + (size_t)(n0 + sr) * 512 + col);
    __syncthreads();
    As[sc][sr] = av.x; As[sc + 1][sr] = av.y; As[sc + 2][sr] = av.z; As[sc + 3][sr] = av.w;
    Bs[sc][sr] = bv.x; Bs[sc + 1][sr] = bv.y; Bs[sc + 2][sr] = bv.z; Bs[sc + 3][sr] = bv.w;
    __syncthreads();
    #pragma unroll
    for (int kk = 0; kk < 16; ++kk) {
      float4 a4 = *(const float4*)&As[kk][4 * ty];
      float4 b4 = *(const float4*)&Bs[kk][4 * tx];
      float a[4] = {a4.x, a4.y, a4.z, a4.w};
      float b[4] = {b4.x, b4.y, b4.z, b4.w};
      #pragma unroll
      for (int i = 0; i < 4; ++i)
        #pragma unroll
        for (int j = 0; j < 4; ++j) acc[i][j] = fmaf(a[i], b[j], acc[i][j]);
    }
  }
  float* Pz = p2 + (size_t)blockIdx.z * 40960;
  #pragma unroll
  for (int i = 0; i < 4; ++i) {
    int m = m0 + 4 * ty + i, n = n0 + 4 * tx;
    if (n < N)
      *(float4*)(Pz + (size_t)m * 160 + n) = make_float4(acc[i][0], acc[i][1], acc[i][2], acc[i][3]);
  }
}

// Finish d2: rx = relu(sum_z p2 + b_d2) * LOG2E, 3-way bf16 split, and ZERO the
// per-col argmax keys (2560 u64; blockIdx covers b, t<10 covers the 10 slate cols).
__global__ __launch_bounds__(256) void rx_prep(const float* __restrict__ p2,
    const float* __restrict__ bd2, float* __restrict__ rx,
    unsigned short* __restrict__ rx0, unsigned short* __restrict__ rx1,
    unsigned short* __restrict__ rx2, unsigned long long* __restrict__ keys) {
  int b = blockIdx.x, t = threadIdx.x;
  if (t < 10) keys[b * 10 + t] = 0ULL;
  if (t >= 160) return;
  float a = bd2[t];
  #pragma unroll
  for (int z = 0; z < 8; ++z) a += p2[(size_t)z * 40960 + b * 160 + t];
  float v = fmaxf(a, 0.f) * LOG2E;
  rx[b * 160 + t] = v;
  int col = b * 10 + (t >> 4), e = t & 15;
  float f0 = bfround(v);
  float d1 = v - f0;            // exact (Sterbenz)
  float f1 = bfround(d1);
  float d2 = d1 - f1;           // exact
  float f2 = bfround(d2);
  rx0[col * 16 + e] = (unsigned short)(__float_as_uint(f0) >> 16);
  rx1[col * 16 + e] = (unsigned short)(__float_as_uint(f1) >> 16);
  rx2[col * 16 + e] = (unsigned short)(__float_as_uint(f2) >> 16);
}

// MFMA scoring: per wave TWO 32-col groups, TPC tiles/chunk, IC=224 chunks.
// Per tile per chain: 16 exp2-sums + fmax tree (tile max) + tile-index select.
// Global (max, tile) via per-col packed atomicMax key = mono(m)<<32 | (2047-tile)
// (max-m wins, ties -> lowest tile = lowest item). Load-filter skips losing
// atomics. S partials -> ps. Item index recovered by argmax_fix (bit-exact rerun).
__global__ __launch_bounds__(256) void score_mfma(const float* __restrict__ emb,
    const unsigned short* __restrict__ rx0, const unsigned short* __restrict__ rx1,
    const unsigned short* __restrict__ rx2,
    float* __restrict__ ps, unsigned long long* __restrict__ keys) {
  int t = threadIdx.x;
  int w = t >> 6, l = t & 63;
  int ln = l & 31, hf = l >> 5;
  int pair = blockIdx.x * 4 + w;   // 0..39 column-pair groups
  int ic = blockIdx.y;             // 0..223 item chunks
  int colA = pair * 64 + ln;       // 0..2559
  int colB = colA + 32;
  size_t offA = (size_t)colA * 16 + hf * 8;
  size_t offB = (size_t)colB * 16 + hf * 8;
  bfrag bA0 = *(const bfrag*)(rx0 + offA);
  bfrag bA1 = *(const bfrag*)(rx1 + offA);
  bfrag bA2 = *(const bfrag*)(rx2 + offA);
  bfrag bB0 = *(const bfrag*)(rx0 + offB);
  bfrag bB1 = *(const bfrag*)(rx1 + offB);
  bfrag bB2 = *(const bfrag*)(rx2 + offB);
  float sA = 0.f, sB = 0.f;
  float mA = -3.402823466e38f, mB = -3.402823466e38f;
  int tlA = 0, tlB = 0;
  int ts = ic * TPC, te = ts + TPC;
  if (te > NT) te = NT;
  #pragma unroll 1
  for (int tile = ts; tile < te; ++tile) {
    int r = tile * 32 + ln;
    float4 e0, e1;
    if (r < NITEMS) {
      const float4* p = (const float4*)(emb + (size_t)r * 16 + hf * 8);
      e0 = p[0]; e1 = p[1];
    } else {
      e0 = make_float4(-128.f, -128.f, -128.f, -128.f);
      e1 = e0;
    }
    float ev[8] = {e0.x, e0.y, e0.z, e0.w, e1.x, e1.y, e1.z, e1.w};
    union { bfrag f; unsigned u[4]; } A0, A1, A2;
    #pragma unroll
    for (int j = 0; j < 4; ++j) {
      float v0 = ev[2 * j], v1 = ev[2 * j + 1];
      unsigned u0 = __float_as_uint(v0), u1 = __float_as_uint(v1);
      A0.u[j] = (u0 >> 16) | (u1 & 0xFFFF0000u);
      float r0 = v0 - __uint_as_float(u0 & 0xFFFF0000u);   // exact
      float r1 = v1 - __uint_as_float(u1 & 0xFFFF0000u);   // exact
      unsigned w0 = __float_as_uint(r0), w1 = __float_as_uint(r1);
      A1.u[j] = (w0 >> 16) | (w1 & 0xFFFF0000u);
      float q0 = r0 - __uint_as_float(w0 & 0xFFFF0000u);   // exact, fits bf16
      float q1 = r1 - __uint_as_float(w1 & 0xFFFF0000u);   // exact, fits bf16
      A2.u[j] = (__float_as_uint(q0) >> 16) | (__float_as_uint(q1) & 0xFFFF0000u);
    }
    f32x16 accA, accB;
    #pragma unroll
    for (int i = 0; i < 16; ++i) { accA[i] = -SHIFT; accB[i] = -SHIFT; }
    // product order per chain identical to verified round-5 kernel
    accA = __builtin_amdgcn_mfma_f32_32x32x16_bf16(A1.f, bA1, accA, 0, 0, 0);
    accB = __builtin_amdgcn_mfma_f32_32x32x16_bf16(A1.f, bB1, accB, 0, 0, 0);
    accA = __builtin_amdgcn_mfma_f32_32x32x16_bf16(A2.f, bA0, accA, 0, 0, 0);
    accB = __builtin_amdgcn_mfma_f32_32x32x16_bf16(A2.f, bB0, accB, 0, 0, 0);
    accA = __builtin_amdgcn_mfma_f32_32x32x16_bf16(A0.f, bA2, accA, 0, 0, 0);
    accB = __builtin_amdgcn_mfma_f32_32x32x16_bf16(A0.f, bB2, accB, 0, 0, 0);
    accA = __builtin_amdgcn_mfma_f32_32x32x16_bf16(A1.f, bA0, accA, 0, 0, 0);
    accB = __builtin_amdgcn_mfma_f32_32x32x16_bf16(A1.f, bB0, accB, 0, 0, 0);
    accA = __builtin_amdgcn_mfma_f32_32x32x16_bf16(A0.f, bA1, accA, 0, 0, 0);
    accB = __builtin_amdgcn_mfma_f32_32x32x16_bf16(A0.f, bB1, accB, 0, 0, 0);
    accA = __builtin_amdgcn_mfma_f32_32x32x16_bf16(A0.f, bA0, accA, 0, 0, 0);
    accB = __builtin_amdgcn_mfma_f32_32x32x16_bf16(A0.f, bB0, accB, 0, 0, 0);
    float tmA, tmB;
    {
      float f1 = FMAX3(accA[0], accA[1], accA[2]);
      float f2 = FMAX3(accA[3], accA[4], accA[5]);
      float f3 = FMAX3(accA[6], accA[7], accA[8]);
      float f4 = FMAX3(accA[9], accA[10], accA[11]);
      float f5 = FMAX3(accA[12], accA[13], accA[14]);
      float g1 = FMAX3(f1, f2, accA[15]);
      float g2 = fmaxf(f3, f4);
      tmA = FMAX3(g1, g2, f5);
    }
    {
      float f1 = FMAX3(accB[0], accB[1], accB[2]);
      float f2 = FMAX3(accB[3], accB[4], accB[5]);
      float f3 = FMAX3(accB[6], accB[7], accB[8]);
      float f4 = FMAX3(accB[9], accB[10], accB[11]);
      float f5 = FMAX3(accB[12], accB[13], accB[14]);
      float g1 = FMAX3(f1, f2, accB[15]);
      float g2 = fmaxf(f3, f4);
      tmB = FMAX3(g1, g2, f5);
    }
    if (tmA > mA) { mA = tmA; tlA = tile; }   // strict > : lowest tile on ties
    if (tmB > mB) { mB = tmB; tlB = tile; }
    #pragma unroll
    for (int i = 0; i < 16; ++i) {
      sA += __builtin_amdgcn_exp2f(accA[i]);
      sB += __builtin_amdgcn_exp2f(accB[i]);
    }
  }
  // lanes (l, l+32) hold the same col, disjoint row sets
  sA += __shfl_xor(sA, 32);
  sB += __shfl_xor(sB, 32);
  {
    float om = __shfl_xor(mA, 32); int ot = __shfl_xor(tlA, 32);
    if (om > mA || (om == mA && ot < tlA)) { mA = om; tlA = ot; }
  }
  {
    float om = __shfl_xor(mB, 32); int ot = __shfl_xor(tlB, 32);
    if (om > mB || (om == mB && ot < tlB)) { mB = om; tlB = ot; }
  }
  if (hf == 0) {
    ps[ic * NCOL + colA] = sA;
    ps[ic * NCOL + colB] = sB;
    unsigned long long kA = ((unsigned long long)mono32(mA) << 32) | (unsigned)(2047 - tlA);
    unsigned long long kB = ((unsigned long long)mono32(mB) << 32) | (unsigned)(2047 - tlB);
    if (kA > keys[colA]) atomicMax(&keys[colA], kA);   // load-filter then atomic
    if (kB > keys[colB]) atomicMax(&keys[colB], kB);
  }
}

// Argmax fixup: grid (80 col-groups, 8 residue classes), 1 wave each. For each col,
// decode (mono_m, tile) from its key; waves with tile%8==k re-run that ONE tile
// through the bit-identical split+MFMA chain and find the lowest row whose value
// bit-matches mono_m. Writes recon_slate.
__global__ __launch_bounds__(64) void argmax_fix(const unsigned long long* __restrict__ keys,
    const unsigned short* __restrict__ rx0, const unsigned short* __restrict__ rx1,
    const unsigned short* __restrict__ rx2, const float* __restrict__ emb,
    float* __restrict__ out) {
  int l = threadIdx.x, ln = l & 31, hf = l >> 5;
  int g = blockIdx.x, k = blockIdx.y;
  int col = g * 32 + ln;
  unsigned long long key = keys[col];
  unsigned um = (unsigned)(key >> 32);
  int tl = 2047 - (int)(key & 0xFFFFFFFFu);
  size_t off = (size_t)col * 16 + hf * 8;
  bfrag b0 = *(const bfrag*)(rx0 + off);
  bfrag b1 = *(const bfrag*)(rx1 + off);
  bfrag b2 = *(const bfrag*)(rx2 + off);
  bool done = ((tl & 7) != k);
  while (true) {
    int tsel = done ? 0x7FFFFFFF : tl;
    #pragma unroll
    for (int o = 32; o > 0; o >>= 1) tsel = min(tsel, __shfl_xor(tsel, o));
    if (tsel == 0x7FFFFFFF) break;
    int r = tsel * 32 + ln;
    float4 e0, e1;
    if (r < NITEMS) {
      const float4* p = (const float4*)(emb + (size_t)r * 16 + hf * 8);
      e0 = p[0]; e1 = p[1];
    } else {
      e0 = make_float4(-128.f, -128.f, -128.f, -128.f);
      e1 = e0;
    }
    float ev[8] = {e0.x, e0.y, e0.z, e0.w, e1.x, e1.y, e1.z, e1.w};
    union { bfrag f; unsigned u[4]; } A0, A1, A2;
    #pragma unroll
    for (int j = 0; j < 4; ++j) {
      float v0 = ev[2 * j], v1 = ev[2 * j + 1];
      unsigned u0 = __float_as_uint(v0), u1 = __float_as_uint(v1);
      A0.u[j] = (u0 >> 16) | (u1 & 0xFFFF0000u);
      float r0 = v0 - __uint_as_float(u0 & 0xFFFF0000u);
      float r1 = v1 - __uint_as_float(u1 & 0xFFFF0000u);
      unsigned w0 = __float_as_uint(r0), w1 = __float_as_uint(r1);
      A1.u[j] = (w0 >> 16) | (w1 & 0xFFFF0000u);
      float q0 = r0 - __uint_as_float(w0 & 0xFFFF0000u);
      float q1 = r1 - __uint_as_float(w1 & 0xFFFF0000u);
      A2.u[j] = (__float_as_uint(q0) >> 16) | (__float_as_uint(q1) & 0xFFFF0000u);
    }
    f32x16 acc;
    #pragma unroll
    for (int i = 0; i < 16; ++i) acc[i] = -SHIFT;
    acc = __builtin_amdgcn_mfma_f32_32x32x16_bf16(A1.f, b1, acc, 0, 0, 0);
    acc = __builtin_amdgcn_mfma_f32_32x32x16_bf16(A2.f, b0, acc, 0, 0, 0);
    acc = __builtin_amdgcn_mfma_f32_32x32x16_bf16(A0.f, b2, acc, 0, 0, 0);
    acc = __builtin_amdgcn_mfma_f32_32x32x16_bf16(A1.f, b0, acc, 0, 0, 0);
    acc = __builtin_amdgcn_mfma_f32_32x32x16_bf16(A0.f, b1, acc, 0, 0, 0);
    acc = __builtin_amdgcn_mfma_f32_32x32x16_bf16(A0.f, b0, acc, 0, 0, 0);
    if (!done && tl == tsel) {
      int best = 0x7FFFFFFF;
      #pragma unroll
      for (int g2 = 0; g2 < 4; ++g2)
        #pragma unroll
        for (int i = 0; i < 4; ++i) {
          float x = acc[g2 * 4 + i];
          int row = 8 * g2 + 4 * hf + i;
          if (mono32(x) == um) best = min(best, tsel * 32 + row);
        }
      int ob = __shfl_xor(best, 32);
      best = min(best, ob);
      if (hf == 0) out[OUT_RS + col] = (float)best;
      done = true;
    }
  }
}

// Combine chunk S-partials (shared fixed shift) + slate prob.
__global__ __launch_bounds__(256) void score_final(const float* __restrict__ psg,
    const float* __restrict__ rx, const float* __restrict__ emb,
    const int* __restrict__ slate, float* __restrict__ out) {
  int tid = blockIdx.x * 256 + threadIdx.x;
  if (tid >= BATCH * 10) return;
  int b = tid / 10, k = tid % 10;
  float S = 0.f;
  for (int c = 0; c < IC; ++c) S += psg[c * NCOL + tid];   // col == tid
  int it = slate[b * 10 + k];
  const float* er = emb + (size_t)it * 16;
  const float* rr = rx + b * 160 + k * 16;  // pre-scaled by LOG2E
  float xs = -SHIFT;
  #pragma unroll
  for (int e = 0; e < 16; ++e) xs = fmaf(rr[e], er[e], xs);
  out[OUT_RR + b * 10 + k] = __builtin_amdgcn_exp2f(xs) / S;
}

extern "C" void kernel_launch(void* const* d_in, const int* in_sizes, int n_in,
                              void* d_out, int out_size, void* d_ws, size_t ws_size,
                              hipStream_t stream) {
  const int* user_repr = (const int*)d_in[0];
  const int* slate = (const int*)d_in[1];
  const float* resp = (const float*)d_in[2];
  const float* eps = (const float*)d_in[3];
  const float* emb = (const float*)d_in[4];
  const float* W_enc = (const float*)d_in[5];
  const float* b_enc = (const float*)d_in[6];
  const float* W_mu = (const float*)d_in[7];
  const float* b_mu = (const float*)d_in[8];
  const float* W_lv = (const float*)d_in[9];
  const float* b_lv = (const float*)d_in[10];
  const float* W_d1 = (const float*)d_in[11];
  const float* b_d1 = (const float*)d_in[12];
  const float* W_d2 = (const float*)d_in[13];
  const float* b_d2 = (const float*)d_in[14];
  float* out = (float*)d_out;
  float* ws = (float*)d_ws;

  float* x    = ws + WS_X;
  float* dz   = ws + WS_DZ;
  float* p2   = ws + WS_P2;
  float* pp   = ws + WS_PP;
  float* part = ws + WS_PART;
  float* ps   = ws + WS_PS;
  unsigned long long* keys = (unsigned long long*)(ws + WS_KEY);
  float* rx   = ws + WS_RX;
  unsigned short* rx0 = (unsigned short*)(ws + WS_RXS0);
  unsigned short* rx1 = (unsigned short*)(ws + WS_RXS1);
  unsigned short* rx2 = (unsigned short*)(ws + WS_RXS2);

  pool_mfma<<<dim3(2, KCH), 256, 0, stream>>>(user_repr, emb, pp);
  build_x<<<256, 256, 0, stream>>>(pp, slate, resp, emb, x, dz);
  gemm64<<<dim3(8, 4, 4), 256, 0, stream>>>(x, W_enc, part, 256, 512, 1200, 300);
  mulv_z_kernel<<<256, 128, 0, stream>>>(part, b_enc, W_mu, b_mu, W_lv, b_lv, eps, out, dz);
  gemm64<<<dim3(8, 4, 4), 256, 0, stream>>>(dz, W_d1, part, 256, 512, 1104, 276);
  gemm_d2<<<dim3(3, 4, 8), 256, 0, stream>>>(part, b_d1, W_d2, p2);
  rx_prep<<<256, 256, 0, stream>>>(p2, b_d2, rx, rx0, rx1, rx2, keys);
  score_mfma<<<dim3(10, IC), 256, 0, stream>>>(emb, rx0, rx1, rx2, ps, keys);
  argmax_fix<<<dim3(80, 8), 64, 0, stream>>>(keys, rx0, rx1, rx2, emb, out);
  score_final<<<10, 256, 0, stream>>>(ps, rx, emb, slate, out);
}